// Round 4
// 9734.433 us; speedup vs baseline: 1.7519x; 1.7519x over previous
//
#include <hip/hip_runtime.h>

#define C_ 128
#define KS_ 9
#define B_ 8
#define H_ 128
#define W_ 256
#define HW_ (H_ * W_)    // 32768
#define CHW_ (C_ * HW_)  // 4194304

typedef _Float16 half8 __attribute__((ext_vector_type(8)));
typedef float floatx4 __attribute__((ext_vector_type(4)));
typedef unsigned long long ull;

// f16 full image = 8*128*128*256*2 B
#define F16_IMG_BYTES 67108864u

// ws layout (primary path)
#define WS_WF_OFF    0u
#define WS_WF_BYTES  1179648u            // 4 passes * 294,912 B fragment weights
#define WS_CARRY_OFF 1183744u            // 2 x [b][col<=256][128ci] f16 = 2 x 524,288 B
#define CARRY_HALVES (8 * 256 * 128)     // 262,144 halves = 524,288 B per parity buffer
#define WS_YT_OFF    2232320u            // f16 image A: 64 MB
#define WS_NEED      (WS_YT_OFF + F16_IMG_BYTES)  // 69,341,184

__device__ __forceinline__ int imin(int a, int b) { return a < b ? a : b; }
__device__ __forceinline__ int imax(int a, int b) { return a > b ? a : b; }

// ---------------- utility kernels ----------------
__global__ void k_copy(const float* __restrict__ in, float* __restrict__ out, int n4) {
  int i = blockIdx.x * blockDim.x + threadIdx.x;
  int stride = gridDim.x * blockDim.x;
  const floatx4* ip = (const floatx4*)in;
  floatx4* op = (floatx4*)out;
  for (; i < n4; i += stride) op[i] = ip[i];
}

// weight prep: fp32 [co][ci][kk] -> f16 A-fragment order
// idx = (((mt8)*36 + ks)*64 + lane)*8 + j ; co = mt8*16 + (lane&15); k = ks*32 + q*8 + j
__global__ void k_wprep(const float* w0, const float* w1, const float* w2, const float* w3,
                        _Float16* __restrict__ wf) {
  const float* Wp[4] = {w0, w1, w2, w3};
  const float* W = Wp[blockIdx.y];
  _Float16* out = wf + (size_t)blockIdx.y * (8 * 36 * 64 * 8);
  int idx = blockIdx.x * 256 + threadIdx.x;
  if (idx >= 8 * 36 * 64 * 8) return;
  int j = idx & 7;
  int lane = (idx >> 3) & 63;
  int ks = (idx >> 9) % 36;
  int mt = (idx >> 9) / 36;
  int co = mt * 16 + (lane & 15);
  int k = ks * 32 + ((lane >> 4) & 3) * 8 + j;
  int kk = k >> 7, ci = k & 127;
  out[idx] = (_Float16)W[((size_t)co * C_ + ci) * KS_ + kk];
}

// initial carry row for a pass: cout[b][col][ci] = (f16) imgX[b][ci][istart][col]
// also writes imgY row istart (y[0] = x[0]).
template <typename XT, typename YT>
__global__ void k_carry0(const XT* __restrict__ imgX, YT* __restrict__ imgY,
                         _Float16* __restrict__ cout_, int S, int L, int istart) {
  int b = blockIdx.y;
  int e = blockIdx.x * 256 + threadIdx.x;  // (col, ci-group-of-8)
  if (e >= L * 16) return;
  int col = e >> 4, ci0 = (e & 15) * 8;
  union { ull u[2]; _Float16 h[8]; } pk;
#pragma unroll
  for (int u2 = 0; u2 < 8; ++u2) {
    size_t off = ((size_t)(b * C_ + ci0 + u2) * S + istart) * L + col;
    float v = (float)imgX[off];
    pk.h[u2] = (_Float16)v;
    imgY[off] = (YT)v;
  }
  ull* dst = (ull*)(cout_ + ((size_t)b * L + col) * 128 + ci0);
  dst[0] = pk.u[0];
  dst[1] = pk.u[1];
}

// transpose f16 [b][c][h][w] -> f16 [b][c][w][h]
__global__ void k_t1h(const _Float16* __restrict__ in, _Float16* __restrict__ out) {
  __shared__ _Float16 tile[32][33];
  size_t pbase = (size_t)blockIdx.z * HW_;
  int h0 = blockIdx.y * 32, w0 = blockIdx.x * 32;
  int tx = threadIdx.x, ty = threadIdx.y;
  for (int i = 0; i < 32; i += 8)
    tile[ty + i][tx] = in[pbase + (size_t)(h0 + ty + i) * W_ + (w0 + tx)];
  __syncthreads();
  for (int i = 0; i < 32; i += 8)
    out[pbase + (size_t)(w0 + ty + i) * H_ + (h0 + tx)] = tile[tx][ty + i];
}

// transpose f16 [b][c][w][h] -> fp32 NCHW
__global__ void k_t2(const _Float16* __restrict__ in, float* __restrict__ out) {
  __shared__ float tile[32][33];
  size_t pbase = (size_t)blockIdx.z * HW_;
  int h0 = blockIdx.y * 32, w0 = blockIdx.x * 32;
  int tx = threadIdx.x, ty = threadIdx.y;
  for (int i = 0; i < 32; i += 8)
    tile[ty + i][tx] = (float)in[pbase + (size_t)(w0 + ty + i) * H_ + (h0 + tx)];
  __syncthreads();
  for (int i = 0; i < 32; i += 8)
    out[pbase + (size_t)(h0 + ty + i) * W_ + (w0 + tx)] = tile[tx][ty + i];
}

// ---------------- trapezoid scan kernel: P=8 steps per launch, no cross-WG sync ----------------
// Each WG owns ALL 128 channels of a WC-col strip of batch b. Carry lives in LDS
// (double-buffered). At launch start: load carry row n0 cols [c0-32, c0+WC+32) from
// cin. Steps p=1..nsteps compute shrinking halo ext = 32-4p redundantly. At launch
// end: publish own strip cols to cout. imgX READ-ONLY, imgY WRITE-ONLY (own strip);
// cin/cout distinct -> zero races; launch boundary is the only synchronization.
template <typename XT, typename YT, int WC, int MAXT>
__global__ __launch_bounds__(256, 1) void k_scan3(
    const XT* __restrict__ imgX, YT* __restrict__ imgY,
    const _Float16* __restrict__ Wf, const _Float16* __restrict__ cin,
    _Float16* __restrict__ cout_,
    int S, int L, int n0, int nsteps, int dir, int istart) {
  constexpr int MAXW = WC + 72;        // cols [c0-36, c0+WC+36); 4-col zero guards each side
  constexpr int BSZ = MAXW * 132;      // row stride 132 halves (proven conflict-light; 8B-aligned)
  __shared__ _Float16 Bl[2][BSZ];
  const int c0 = blockIdx.x * WC;
  const int b = blockIdx.y;
  const int t = threadIdx.x;
  const int lane = t & 63, wave = t >> 6;
  const int q = lane >> 4, m = lane & 15;

  // A-fragments: wave w owns m-tiles {2w, 2w+1} (co = wave*32 .. +32)
  half8 A0[36], A1[36];
  {
    const half8* wp2 = (const half8*)Wf;
#pragma unroll
    for (int ks = 0; ks < 36; ++ks) {
      A0[ks] = wp2[((wave * 2 + 0) * 36 + ks) * 64 + lane];
      A1[ks] = wp2[((wave * 2 + 1) * 36 + ks) * 64 + lane];
    }
  }

  // zero both LDS buffers (establishes conv zero-padding guards)
  // i indexes halves in slots of 8; one ull = 4 halves -> two stores per buffer.
  for (int i = t * 8; i < BSZ; i += 2048) {
    ull* z0 = (ull*)(&Bl[0][i]);
    ull* z1 = (ull*)(&Bl[1][i]);
    z0[0] = 0ull; z0[1] = 0ull;
    z1[0] = 0ull; z1[1] = 0ull;
  }
  __syncthreads();

  // load carry row n0: cols [c0-32, c0+WC+32) ∩ [0,L) into Bl[0]
  {
    const int NCH = (WC + 64) * 16;
    for (int e = t; e < NCH; e += 256) {
      const int lcol = e >> 4;
      const int col = c0 - 32 + lcol;
      if (col >= 0 && col < L) {
        const int ci0 = (e & 15) * 8;
        const ull* src = (const ull*)(cin + ((size_t)b * L + col) * 128 + ci0);
        ull* dst = (ull*)(&Bl[0][(lcol + 4) * 132 + ci0]);
        dst[0] = src[0];
        dst[1] = src[1];
      }
    }
  }
  __syncthreads();

  int cur = 0;
  for (int p = 1; p <= nsteps; ++p) {
    const int row = istart + dir * (n0 + p);
    const int ext = 32 - 4 * p;  // valid halo width this step
    const int lo = imax(c0 - ext, 0);
    const int hi = imin(c0 + WC + ext, L);
    const int tt0 = -((c0 - lo + 15) >> 4);
    const int ntile = ((hi - c0 + 15) >> 4) - tt0;
    const _Float16* BR = Bl[cur];
    _Float16* BW = Bl[cur ^ 1];
    const size_t rbase = ((size_t)(b * C_ + wave * 32) * S + row) * L;

    // x for tile 0 (rotating 2-deep register pipeline; static indices only)
    float xcur[8], xnxt[8];
    {
      const int col = c0 + tt0 * 16 + m;
      const bool ld = (col >= lo) && (col < hi);
#pragma unroll
      for (int j = 0; j < 8; ++j)
        xcur[j] = ld ? (float)imgX[rbase + (size_t)((j >> 2) * 16 + q * 4 + (j & 3)) * S * L + col]
                     : 0.f;
    }

#pragma unroll
    for (int u = 0; u < MAXT; ++u) {
      if (u >= ntile) break;  // uniform per-WG trip count
      const int ti = tt0 + u;
      // prefetch next tile's x under this tile's GEMM
      if (u + 1 < ntile) {
        const int coln = c0 + (ti + 1) * 16 + m;
        const bool ldn = (coln >= lo) && (coln < hi);
#pragma unroll
        for (int j = 0; j < 8; ++j)
          xnxt[j] = ldn ? (float)imgX[rbase + (size_t)((j >> 2) * 16 + q * 4 + (j & 3)) * S * L + coln]
                        : 0.f;
      }
      // GEMM: 32 co x 1152 K x 16 cols
      floatx4 a0 = {0.f, 0.f, 0.f, 0.f}, a1 = {0.f, 0.f, 0.f, 0.f};
      const int lbase = ti * 16 + m + 32;  // lcol for kk=0 tap (col + kk - 4 -> +36-4)
#pragma unroll
      for (int ks = 0; ks < 36; ++ks) {
        const int kk = ks >> 2;
        const int ci0 = (ks & 3) * 32 + q * 8;
        // 132-half row stride is only 8B-aligned: load as 2x ull (ds_read_b64), not half8
        const ull* bp = (const ull*)(BR + (lbase + kk) * 132 + ci0);
        union { ull u[2]; half8 v; } bf;
        bf.u[0] = bp[0];
        bf.u[1] = bp[1];
        a0 = __builtin_amdgcn_mfma_f32_16x16x32_f16(A0[ks], bf.v, a0, 0, 0, 0);
        a1 = __builtin_amdgcn_mfma_f32_16x16x32_f16(A1[ks], bf.v, a1, 0, 0, 0);
      }
      // epilogue: y = x + relu(conv); img store (own strip) + LDS store (valid range)
      const int col = c0 + ti * 16 + m;
      const bool instrip = (col >= c0) && (col < c0 + WC);
      const bool inlds = (col >= lo) && (col < hi);
#pragma unroll
      for (int mt = 0; mt < 2; ++mt) {
        union { ull uu; _Float16 h[4]; } pk;
        const floatx4 av = mt ? a1 : a0;
#pragma unroll
        for (int r = 0; r < 4; ++r) {
          const float y = xcur[mt * 4 + r] + fmaxf(av[r], 0.f);
          pk.h[r] = (_Float16)y;
          if (instrip)
            __builtin_nontemporal_store(
                (YT)y, imgY + rbase + (size_t)(mt * 16 + q * 4 + r) * S * L + col);
        }
        if (inlds)
          *(ull*)(BW + (col - c0 + 36) * 132 + wave * 32 + mt * 16 + q * 4) = pk.uu;
      }
#pragma unroll
      for (int j = 0; j < 8; ++j) xcur[j] = xnxt[j];
    }
    __syncthreads();  // one barrier per step: BW complete before it becomes BR
    cur ^= 1;
  }

  // publish own strip's carry (row n0+nsteps) for the next launch
  // NOTE: each (lc, ci-group) is EIGHT halves = two ull copies.
  {
    const _Float16* BP = Bl[cur];
    for (int e = t; e < WC * 16; e += 256) {
      const int lc = e >> 4, ci0 = (e & 15) * 8;
      ull* dst = (ull*)(cout_ + ((size_t)b * L + (c0 + lc)) * 128 + ci0);
      const ull* src = (const ull*)(BP + (lc + 36) * 132 + ci0);
      dst[0] = src[0];
      dst[1] = src[1];
    }
  }
}

// ---------------- fallback path (round-2, proven): per-step kernels ----------------
__device__ __forceinline__ void gemm_acc_fb(const _Float16* Bl, const _Float16* __restrict__ Wfrag,
                                            int wrow_base, int lane, floatx4* acc) {
  const int q = lane >> 4;
  const half8* wfp = (const half8*)Wfrag + lane;
  for (int ks = 0; ks < 36; ++ks) {
    int k0 = ks * 32 + q * 8;
    int kk = k0 >> 7;
    int ci0 = k0 & 127;
    half8 bf = *(const half8*)&Bl[(size_t)(wrow_base + kk) * C_ + ci0];
    const half8* wp = wfp + ks * 64;
#pragma unroll
    for (int mt = 0; mt < 8; ++mt)
      acc[mt] = __builtin_amdgcn_mfma_f32_16x16x32_f16(wp[mt * 36 * 64], bf, acc[mt], 0, 0, 0);
  }
}

__global__ __launch_bounds__(256) void k_step_v(float* __restrict__ Y,
                                                const _Float16* __restrict__ Wfrag,
                                                int row, int prev) {
  __shared__ _Float16 Bl[80 * 128];
  const int b = blockIdx.y, w0 = blockIdx.x * 64, t = threadIdx.x;
  {
    const float* base = Y + (size_t)b * CHW_ + (size_t)prev * W_;
#pragma unroll
    for (int it = 0; it < 10; ++it) {
      int c = it * 256 + t;
      int ci = c / 20, c4 = c % 20;
      int wst = w0 - 8 + c4 * 4;
      const float* p = base + (size_t)ci * HW_ + wst;
      float v[4];
      if (wst >= 0 && wst + 4 <= W_) {
        floatx4 u = *(const floatx4*)p;
        v[0] = u[0]; v[1] = u[1]; v[2] = u[2]; v[3] = u[3];
      } else {
#pragma unroll
        for (int j = 0; j < 4; ++j) { int w = wst + j; v[j] = (w >= 0 && w < W_) ? p[j] : 0.f; }
      }
      int wl = c4 * 4;
#pragma unroll
      for (int j = 0; j < 4; ++j) Bl[(wl + j) * C_ + ci] = (_Float16)v[j];
    }
  }
  __syncthreads();
  const int lane = t & 63, wave = t >> 6, q = lane >> 4, l15 = lane & 15;
  floatx4 acc[8];
#pragma unroll
  for (int mt = 0; mt < 8; ++mt) acc[mt] = (floatx4){0.f, 0.f, 0.f, 0.f};
  gemm_acc_fb(Bl, Wfrag, wave * 16 + l15 + 4, lane, acc);
  const int wcol = w0 + wave * 16 + l15;
#pragma unroll
  for (int mt = 0; mt < 8; ++mt)
#pragma unroll
    for (int r = 0; r < 4; ++r) {
      int co = mt * 16 + q * 4 + r;
      size_t off = (size_t)b * CHW_ + (size_t)co * HW_ + (size_t)row * W_ + wcol;
      Y[off] = Y[off] + fmaxf(acc[mt][r], 0.f);
    }
}

__global__ __launch_bounds__(256) void k_step_h(float* __restrict__ Y,
                                                const _Float16* __restrict__ Wfrag,
                                                int row, int prev) {
  __shared__ _Float16 Bl[80 * 128];
  const int b = blockIdx.y, h0 = blockIdx.x * 64, t = threadIdx.x;
  {
    const float* base = Y + (size_t)b * CHW_ + prev;
    for (int e = t; e < 80 * 128; e += 256) {
      int hl = e >> 7, ci = e & 127, h = h0 - 8 + hl;
      float v = 0.f;
      if (h >= 0 && h < H_) v = base[(size_t)ci * HW_ + (size_t)h * W_];
      Bl[hl * C_ + ci] = (_Float16)v;
    }
  }
  __syncthreads();
  const int lane = t & 63, wave = t >> 6, q = lane >> 4, l15 = lane & 15;
  floatx4 acc[8];
#pragma unroll
  for (int mt = 0; mt < 8; ++mt) acc[mt] = (floatx4){0.f, 0.f, 0.f, 0.f};
  gemm_acc_fb(Bl, Wfrag, wave * 16 + l15 + 4, lane, acc);
  const int hc = h0 + wave * 16 + l15;
#pragma unroll
  for (int mt = 0; mt < 8; ++mt)
#pragma unroll
    for (int r = 0; r < 4; ++r) {
      int co = mt * 16 + q * 4 + r;
      size_t off = (size_t)b * CHW_ + (size_t)co * HW_ + (size_t)hc * W_ + row;
      Y[off] = Y[off] + fmaxf(acc[mt][r], 0.f);
    }
}

extern "C" void kernel_launch(void* const* d_in, const int* in_sizes, int n_in,
                              void* d_out, int out_size, void* d_ws, size_t ws_size,
                              hipStream_t stream) {
  const float* x = (const float*)d_in[0];
  const float* w_ud = (const float*)d_in[1];
  const float* w_du = (const float*)d_in[2];
  const float* w_lr = (const float*)d_in[3];
  const float* w_rl = (const float*)d_in[4];

  float* Y = (float*)d_out;  // f32 image (P1 out / P2 in); scratch later
  char* ws = (char*)d_ws;
  _Float16* Wf = (_Float16*)(ws + WS_WF_OFF);
  _Float16* carryA = (_Float16*)(ws + WS_CARRY_OFF);          // parity 0
  _Float16* carryB = carryA + CARRY_HALVES;                    // parity 1
  _Float16* YtA = (_Float16*)(ws + WS_YT_OFF);                 // 64 MB f16 image (ws)
  _Float16* F16A = (_Float16*)d_out;                           // [0, 64 MB) of d_out
  _Float16* F16B = (_Float16*)((char*)d_out + F16_IMG_BYTES);  // [64, 128 MB) of d_out

  const size_t WF_PASS = 8 * 36 * 64 * 8;

  k_wprep<<<dim3(576, 4), 256, 0, stream>>>(w_ud, w_du, w_lr, w_rl, Wf);

  if (ws_size >= WS_NEED) {
    // ---- primary: trapezoid scan, launch boundary every 8 steps ----
    _Float16* cb_[2] = {carryA, carryB};
    // P1: vertical fwd, x = d_in (f32, read-only), y = d_out (f32)
    k_carry0<float, float><<<dim3(16, B_), 256, 0, stream>>>(x, Y, carryA, H_, W_, 0);
    for (int n0 = 0, j = 0; n0 < H_ - 1; n0 += 8, ++j) {
      int ns = H_ - 1 - n0; if (ns > 8) ns = 8;
      k_scan3<float, float, 32, 6><<<dim3(8, B_), 256, 0, stream>>>(
          x, Y, Wf + 0 * WF_PASS, cb_[j & 1], cb_[(j + 1) & 1], H_, W_, n0, ns, +1, 0);
    }
    // P2: vertical bwd, x = d_out (f32), y = YtA (f16) [= old t1 quantization point]
    k_carry0<float, _Float16><<<dim3(16, B_), 256, 0, stream>>>(Y, YtA, carryA, H_, W_, H_ - 1);
    for (int n0 = 0, j = 0; n0 < H_ - 1; n0 += 8, ++j) {
      int ns = H_ - 1 - n0; if (ns > 8) ns = 8;
      k_scan3<float, _Float16, 32, 6><<<dim3(8, B_), 256, 0, stream>>>(
          Y, YtA, Wf + 1 * WF_PASS, cb_[j & 1], cb_[(j + 1) & 1], H_, W_, n0, ns, -1, H_ - 1);
    }
    // transpose YtA [b][c][h][w] -> F16A [b][c][w][h]
    k_t1h<<<dim3(8, 4, B_ * C_), dim3(32, 8), 0, stream>>>(YtA, F16A);
    // P3: horizontal fwd, x = F16A, y = YtA (transposed layout: S=W, L=H)
    k_carry0<_Float16, _Float16><<<dim3(8, B_), 256, 0, stream>>>(F16A, YtA, carryA, W_, H_, 0);
    for (int n0 = 0, j = 0; n0 < W_ - 1; n0 += 8, ++j) {
      int ns = W_ - 1 - n0; if (ns > 8) ns = 8;
      k_scan3<_Float16, _Float16, 16, 5><<<dim3(8, B_), 256, 0, stream>>>(
          F16A, YtA, Wf + 2 * WF_PASS, cb_[j & 1], cb_[(j + 1) & 1], W_, H_, n0, ns, +1, 0);
    }
    // P4: horizontal bwd, x = YtA, y = F16B
    k_carry0<_Float16, _Float16><<<dim3(8, B_), 256, 0, stream>>>(YtA, F16B, carryA, W_, H_, W_ - 1);
    for (int n0 = 0, j = 0; n0 < W_ - 1; n0 += 8, ++j) {
      int ns = W_ - 1 - n0; if (ns > 8) ns = 8;
      k_scan3<_Float16, _Float16, 16, 5><<<dim3(8, B_), 256, 0, stream>>>(
          YtA, F16B, Wf + 3 * WF_PASS, cb_[j & 1], cb_[(j + 1) & 1], W_, H_, n0, ns, -1, W_ - 1);
    }
    // move P4 result out of d_out (k_t2 will overwrite all of d_out), then back-transpose
    k_copy<<<2048, 256, 0, stream>>>((const float*)F16B, (float*)YtA, F16_IMG_BYTES / 16);
    k_t2<<<dim3(8, 4, B_ * C_), dim3(32, 8), 0, stream>>>(YtA, Y);
  } else {
    // ---- fallback: proven per-step path ----
    k_copy<<<2048, 256, 0, stream>>>(x, Y, B_ * C_ * H_ * W_ / 4);
    for (int i = 1; i < H_; ++i)
      k_step_v<<<dim3(W_ / 64, B_), 256, 0, stream>>>(Y, Wf + 0 * WF_PASS, i, i - 1);
    for (int i = H_ - 2; i >= 0; --i)
      k_step_v<<<dim3(W_ / 64, B_), 256, 0, stream>>>(Y, Wf + 1 * WF_PASS, i, i + 1);
    for (int i = 1; i < W_; ++i)
      k_step_h<<<dim3(H_ / 64, B_), 256, 0, stream>>>(Y, Wf + 2 * WF_PASS, i, i - 1);
    for (int i = W_ - 2; i >= 0; --i)
      k_step_h<<<dim3(H_ / 64, B_), 256, 0, stream>>>(Y, Wf + 3 * WF_PASS, i, i + 1);
  }
}

// Round 5
// 9699.411 us; speedup vs baseline: 1.7582x; 1.0036x over previous
//
#include <hip/hip_runtime.h>

#define C_ 128
#define KS_ 9
#define B_ 8
#define H_ 128
#define W_ 256
#define HW_ (H_ * W_)    // 32768
#define CHW_ (C_ * HW_)  // 4194304

typedef _Float16 half8 __attribute__((ext_vector_type(8)));
typedef float floatx4 __attribute__((ext_vector_type(4)));
typedef unsigned long long ull;

// f16 full image = 8*128*128*256*2 B
#define F16_IMG_BYTES 67108864u

// ws layout (primary path)
#define WS_WF_OFF    0u
#define WS_WF_BYTES  1179648u            // 4 passes * 294,912 B fragment weights
#define WS_CARRY_OFF 1183744u            // 2 x [b][col<=256][128ci] f16 = 2 x 524,288 B
#define CARRY_HALVES (8 * 256 * 128)     // 262,144 halves = 524,288 B per parity buffer
#define WS_YT_OFF    2232320u            // f16 image A: 64 MB
#define WS_NEED      (WS_YT_OFF + F16_IMG_BYTES)  // 69,341,184

__device__ __forceinline__ int imin(int a, int b) { return a < b ? a : b; }
__device__ __forceinline__ int imax(int a, int b) { return a > b ? a : b; }

// ---------------- utility kernels ----------------
__global__ void k_copy(const float* __restrict__ in, float* __restrict__ out, int n4) {
  int i = blockIdx.x * blockDim.x + threadIdx.x;
  int stride = gridDim.x * blockDim.x;
  const floatx4* ip = (const floatx4*)in;
  floatx4* op = (floatx4*)out;
  for (; i < n4; i += stride) op[i] = ip[i];
}

// weight prep: fp32 [co][ci][kk] -> f16 A-fragment order
// idx = (((mt8)*36 + ks)*64 + lane)*8 + j ; co = mt8*16 + (lane&15); k = ks*32 + q*8 + j
__global__ void k_wprep(const float* w0, const float* w1, const float* w2, const float* w3,
                        _Float16* __restrict__ wf) {
  const float* Wp[4] = {w0, w1, w2, w3};
  const float* W = Wp[blockIdx.y];
  _Float16* out = wf + (size_t)blockIdx.y * (8 * 36 * 64 * 8);
  int idx = blockIdx.x * 256 + threadIdx.x;
  if (idx >= 8 * 36 * 64 * 8) return;
  int j = idx & 7;
  int lane = (idx >> 3) & 63;
  int ks = (idx >> 9) % 36;
  int mt = (idx >> 9) / 36;
  int co = mt * 16 + (lane & 15);
  int k = ks * 32 + ((lane >> 4) & 3) * 8 + j;
  int kk = k >> 7, ci = k & 127;
  out[idx] = (_Float16)W[((size_t)co * C_ + ci) * KS_ + kk];
}

// initial carry row for a pass: cout[b][col][ci] = (f16) imgX[b][ci][istart][col]
// also writes imgY row istart (y[0] = x[0]).
template <typename XT, typename YT>
__global__ void k_carry0(const XT* __restrict__ imgX, YT* __restrict__ imgY,
                         _Float16* __restrict__ cout_, int S, int L, int istart) {
  int b = blockIdx.y;
  int e = blockIdx.x * 256 + threadIdx.x;  // (col, ci-group-of-8)
  if (e >= L * 16) return;
  int col = e >> 4, ci0 = (e & 15) * 8;
  union { ull u[2]; _Float16 h[8]; } pk;
#pragma unroll
  for (int u2 = 0; u2 < 8; ++u2) {
    size_t off = ((size_t)(b * C_ + ci0 + u2) * S + istart) * L + col;
    float v = (float)imgX[off];
    pk.h[u2] = (_Float16)v;
    imgY[off] = (YT)v;
  }
  ull* dst = (ull*)(cout_ + ((size_t)b * L + col) * 128 + ci0);
  dst[0] = pk.u[0];
  dst[1] = pk.u[1];
}

// transpose f16 [b][c][h][w] -> f16 [b][c][w][h]
__global__ void k_t1h(const _Float16* __restrict__ in, _Float16* __restrict__ out) {
  __shared__ _Float16 tile[32][33];
  size_t pbase = (size_t)blockIdx.z * HW_;
  int h0 = blockIdx.y * 32, w0 = blockIdx.x * 32;
  int tx = threadIdx.x, ty = threadIdx.y;
  for (int i = 0; i < 32; i += 8)
    tile[ty + i][tx] = in[pbase + (size_t)(h0 + ty + i) * W_ + (w0 + tx)];
  __syncthreads();
  for (int i = 0; i < 32; i += 8)
    out[pbase + (size_t)(w0 + ty + i) * H_ + (h0 + tx)] = tile[tx][ty + i];
}

// transpose f16 [b][c][w][h] -> fp32 NCHW
__global__ void k_t2(const _Float16* __restrict__ in, float* __restrict__ out) {
  __shared__ float tile[32][33];
  size_t pbase = (size_t)blockIdx.z * HW_;
  int h0 = blockIdx.y * 32, w0 = blockIdx.x * 32;
  int tx = threadIdx.x, ty = threadIdx.y;
  for (int i = 0; i < 32; i += 8)
    tile[ty + i][tx] = (float)in[pbase + (size_t)(w0 + ty + i) * H_ + (h0 + tx)];
  __syncthreads();
  for (int i = 0; i < 32; i += 8)
    out[pbase + (size_t)(h0 + ty + i) * W_ + (w0 + tx)] = tile[tx][ty + i];
}

// ---------------- trapezoid scan kernel: P=8 steps per launch, no cross-WG sync ----------------
// Each WG owns ALL 128 channels of a WC-col strip of batch b. Carry lives in LDS
// (double-buffered). At launch start: load carry row n0 cols [c0-32, c0+WC+32) from
// cin. Steps p=1..nsteps compute shrinking halo ext = 32-4p redundantly. At launch
// end: publish own strip cols to cout. imgX READ-ONLY, imgY WRITE-ONLY (own strip);
// cin/cout distinct -> zero races; launch boundary is the only synchronization.
// NOTE: imgY stores are PLAIN (not nontemporal): the next pass/launch re-reads this
// data, so it must stay L2/L3-resident. NT stores here cost ~3x (HBM round trip).
template <typename XT, typename YT, int WC, int MAXT>
__global__ __launch_bounds__(256, 1) void k_scan3(
    const XT* __restrict__ imgX, YT* __restrict__ imgY,
    const _Float16* __restrict__ Wf, const _Float16* __restrict__ cin,
    _Float16* __restrict__ cout_,
    int S, int L, int n0, int nsteps, int dir, int istart) {
  constexpr int MAXW = WC + 72;        // cols [c0-36, c0+WC+36); 4-col zero guards each side
  constexpr int BSZ = MAXW * 132;      // row stride 132 halves (proven conflict-light; 8B-aligned)
  __shared__ _Float16 Bl[2][BSZ];
  const int c0 = blockIdx.x * WC;
  const int b = blockIdx.y;
  const int t = threadIdx.x;
  const int lane = t & 63, wave = t >> 6;
  const int q = lane >> 4, m = lane & 15;

  // A-fragments: wave w owns m-tiles {2w, 2w+1} (co = wave*32 .. +32)
  half8 A0[36], A1[36];
  {
    const half8* wp2 = (const half8*)Wf;
#pragma unroll
    for (int ks = 0; ks < 36; ++ks) {
      A0[ks] = wp2[((wave * 2 + 0) * 36 + ks) * 64 + lane];
      A1[ks] = wp2[((wave * 2 + 1) * 36 + ks) * 64 + lane];
    }
  }

  // zero both LDS buffers (establishes conv zero-padding guards)
  // i indexes halves in slots of 8; one ull = 4 halves -> two stores per buffer.
  for (int i = t * 8; i < BSZ; i += 2048) {
    ull* z0 = (ull*)(&Bl[0][i]);
    ull* z1 = (ull*)(&Bl[1][i]);
    z0[0] = 0ull; z0[1] = 0ull;
    z1[0] = 0ull; z1[1] = 0ull;
  }
  __syncthreads();

  // load carry row n0: cols [c0-32, c0+WC+32) ∩ [0,L) into Bl[0]
  {
    const int NCH = (WC + 64) * 16;
    for (int e = t; e < NCH; e += 256) {
      const int lcol = e >> 4;
      const int col = c0 - 32 + lcol;
      if (col >= 0 && col < L) {
        const int ci0 = (e & 15) * 8;
        const ull* src = (const ull*)(cin + ((size_t)b * L + col) * 128 + ci0);
        ull* dst = (ull*)(&Bl[0][(lcol + 4) * 132 + ci0]);
        dst[0] = src[0];
        dst[1] = src[1];
      }
    }
  }
  __syncthreads();

  int cur = 0;
  for (int p = 1; p <= nsteps; ++p) {
    const int row = istart + dir * (n0 + p);
    const int ext = 32 - 4 * p;  // valid halo width this step
    const int lo = imax(c0 - ext, 0);
    const int hi = imin(c0 + WC + ext, L);
    const int tt0 = -((c0 - lo + 15) >> 4);
    const int ntile = ((hi - c0 + 15) >> 4) - tt0;
    const _Float16* BR = Bl[cur];
    _Float16* BW = Bl[cur ^ 1];
    const size_t rbase = ((size_t)(b * C_ + wave * 32) * S + row) * L;

    // x for tile 0 (rotating 2-deep register pipeline; static indices only)
    float xcur[8], xnxt[8];
    {
      const int col = c0 + tt0 * 16 + m;
      const bool ld = (col >= lo) && (col < hi);
#pragma unroll
      for (int j = 0; j < 8; ++j)
        xcur[j] = ld ? (float)imgX[rbase + (size_t)((j >> 2) * 16 + q * 4 + (j & 3)) * S * L + col]
                     : 0.f;
    }

#pragma unroll
    for (int u = 0; u < MAXT; ++u) {
      if (u >= ntile) break;  // uniform per-WG trip count
      const int ti = tt0 + u;
      // prefetch next tile's x under this tile's GEMM
      if (u + 1 < ntile) {
        const int coln = c0 + (ti + 1) * 16 + m;
        const bool ldn = (coln >= lo) && (coln < hi);
#pragma unroll
        for (int j = 0; j < 8; ++j)
          xnxt[j] = ldn ? (float)imgX[rbase + (size_t)((j >> 2) * 16 + q * 4 + (j & 3)) * S * L + coln]
                        : 0.f;
      }
      // GEMM: 32 co x 1152 K x 16 cols
      floatx4 a0 = {0.f, 0.f, 0.f, 0.f}, a1 = {0.f, 0.f, 0.f, 0.f};
      const int lbase = ti * 16 + m + 32;  // lcol for kk=0 tap (col + kk - 4 -> +36-4)
#pragma unroll
      for (int ks = 0; ks < 36; ++ks) {
        const int kk = ks >> 2;
        const int ci0 = (ks & 3) * 32 + q * 8;
        // 132-half row stride is only 8B-aligned: load as 2x ull (ds_read_b64), not half8
        const ull* bp = (const ull*)(BR + (lbase + kk) * 132 + ci0);
        union { ull u[2]; half8 v; } bf;
        bf.u[0] = bp[0];
        bf.u[1] = bp[1];
        a0 = __builtin_amdgcn_mfma_f32_16x16x32_f16(A0[ks], bf.v, a0, 0, 0, 0);
        a1 = __builtin_amdgcn_mfma_f32_16x16x32_f16(A1[ks], bf.v, a1, 0, 0, 0);
      }
      // epilogue: y = x + relu(conv); img store (own strip) + LDS store (valid range)
      const int col = c0 + ti * 16 + m;
      const bool instrip = (col >= c0) && (col < c0 + WC);
      const bool inlds = (col >= lo) && (col < hi);
#pragma unroll
      for (int mt = 0; mt < 2; ++mt) {
        union { ull uu; _Float16 h[4]; } pk;
        const floatx4 av = mt ? a1 : a0;
#pragma unroll
        for (int r = 0; r < 4; ++r) {
          const float y = xcur[mt * 4 + r] + fmaxf(av[r], 0.f);
          pk.h[r] = (_Float16)y;
          if (instrip)
            imgY[rbase + (size_t)(mt * 16 + q * 4 + r) * S * L + col] = (YT)y;
        }
        if (inlds)
          *(ull*)(BW + (col - c0 + 36) * 132 + wave * 32 + mt * 16 + q * 4) = pk.uu;
      }
#pragma unroll
      for (int j = 0; j < 8; ++j) xcur[j] = xnxt[j];
    }
    __syncthreads();  // one barrier per step: BW complete before it becomes BR
    cur ^= 1;
  }

  // publish own strip's carry (row n0+nsteps) for the next launch
  // NOTE: each (lc, ci-group) is EIGHT halves = two ull copies.
  {
    const _Float16* BP = Bl[cur];
    for (int e = t; e < WC * 16; e += 256) {
      const int lc = e >> 4, ci0 = (e & 15) * 8;
      ull* dst = (ull*)(cout_ + ((size_t)b * L + (c0 + lc)) * 128 + ci0);
      const ull* src = (const ull*)(BP + (lc + 36) * 132 + ci0);
      dst[0] = src[0];
      dst[1] = src[1];
    }
  }
}

// ---------------- fallback path (round-2, proven): per-step kernels ----------------
__device__ __forceinline__ void gemm_acc_fb(const _Float16* Bl, const _Float16* __restrict__ Wfrag,
                                            int wrow_base, int lane, floatx4* acc) {
  const int q = lane >> 4;
  const half8* wfp = (const half8*)Wfrag + lane;
  for (int ks = 0; ks < 36; ++ks) {
    int k0 = ks * 32 + q * 8;
    int kk = k0 >> 7;
    int ci0 = k0 & 127;
    half8 bf = *(const half8*)&Bl[(size_t)(wrow_base + kk) * C_ + ci0];
    const half8* wp = wfp + ks * 64;
#pragma unroll
    for (int mt = 0; mt < 8; ++mt)
      acc[mt] = __builtin_amdgcn_mfma_f32_16x16x32_f16(wp[mt * 36 * 64], bf, acc[mt], 0, 0, 0);
  }
}

__global__ __launch_bounds__(256) void k_step_v(float* __restrict__ Y,
                                                const _Float16* __restrict__ Wfrag,
                                                int row, int prev) {
  __shared__ _Float16 Bl[80 * 128];
  const int b = blockIdx.y, w0 = blockIdx.x * 64, t = threadIdx.x;
  {
    const float* base = Y + (size_t)b * CHW_ + (size_t)prev * W_;
#pragma unroll
    for (int it = 0; it < 10; ++it) {
      int c = it * 256 + t;
      int ci = c / 20, c4 = c % 20;
      int wst = w0 - 8 + c4 * 4;
      const float* p = base + (size_t)ci * HW_ + wst;
      float v[4];
      if (wst >= 0 && wst + 4 <= W_) {
        floatx4 u = *(const floatx4*)p;
        v[0] = u[0]; v[1] = u[1]; v[2] = u[2]; v[3] = u[3];
      } else {
#pragma unroll
        for (int j = 0; j < 4; ++j) { int w = wst + j; v[j] = (w >= 0 && w < W_) ? p[j] : 0.f; }
      }
      int wl = c4 * 4;
#pragma unroll
      for (int j = 0; j < 4; ++j) Bl[(wl + j) * C_ + ci] = (_Float16)v[j];
    }
  }
  __syncthreads();
  const int lane = t & 63, wave = t >> 6, q = lane >> 4, l15 = lane & 15;
  floatx4 acc[8];
#pragma unroll
  for (int mt = 0; mt < 8; ++mt) acc[mt] = (floatx4){0.f, 0.f, 0.f, 0.f};
  gemm_acc_fb(Bl, Wfrag, wave * 16 + l15 + 4, lane, acc);
  const int wcol = w0 + wave * 16 + l15;
#pragma unroll
  for (int mt = 0; mt < 8; ++mt)
#pragma unroll
    for (int r = 0; r < 4; ++r) {
      int co = mt * 16 + q * 4 + r;
      size_t off = (size_t)b * CHW_ + (size_t)co * HW_ + (size_t)row * W_ + wcol;
      Y[off] = Y[off] + fmaxf(acc[mt][r], 0.f);
    }
}

__global__ __launch_bounds__(256) void k_step_h(float* __restrict__ Y,
                                                const _Float16* __restrict__ Wfrag,
                                                int row, int prev) {
  __shared__ _Float16 Bl[80 * 128];
  const int b = blockIdx.y, h0 = blockIdx.x * 64, t = threadIdx.x;
  {
    const float* base = Y + (size_t)b * CHW_ + prev;
    for (int e = t; e < 80 * 128; e += 256) {
      int hl = e >> 7, ci = e & 127, h = h0 - 8 + hl;
      float v = 0.f;
      if (h >= 0 && h < H_) v = base[(size_t)ci * HW_ + (size_t)h * W_];
      Bl[hl * C_ + ci] = (_Float16)v;
    }
  }
  __syncthreads();
  const int lane = t & 63, wave = t >> 6, q = lane >> 4, l15 = lane & 15;
  floatx4 acc[8];
#pragma unroll
  for (int mt = 0; mt < 8; ++mt) acc[mt] = (floatx4){0.f, 0.f, 0.f, 0.f};
  gemm_acc_fb(Bl, Wfrag, wave * 16 + l15 + 4, lane, acc);
  const int hc = h0 + wave * 16 + l15;
#pragma unroll
  for (int mt = 0; mt < 8; ++mt)
#pragma unroll
    for (int r = 0; r < 4; ++r) {
      int co = mt * 16 + q * 4 + r;
      size_t off = (size_t)b * CHW_ + (size_t)co * HW_ + (size_t)hc * W_ + row;
      Y[off] = Y[off] + fmaxf(acc[mt][r], 0.f);
    }
}

extern "C" void kernel_launch(void* const* d_in, const int* in_sizes, int n_in,
                              void* d_out, int out_size, void* d_ws, size_t ws_size,
                              hipStream_t stream) {
  const float* x = (const float*)d_in[0];
  const float* w_ud = (const float*)d_in[1];
  const float* w_du = (const float*)d_in[2];
  const float* w_lr = (const float*)d_in[3];
  const float* w_rl = (const float*)d_in[4];

  float* Y = (float*)d_out;  // f32 image (P1 out / P2 in); scratch later
  char* ws = (char*)d_ws;
  _Float16* Wf = (_Float16*)(ws + WS_WF_OFF);
  _Float16* carryA = (_Float16*)(ws + WS_CARRY_OFF);          // parity 0
  _Float16* carryB = carryA + CARRY_HALVES;                    // parity 1
  _Float16* YtA = (_Float16*)(ws + WS_YT_OFF);                 // 64 MB f16 image (ws)
  _Float16* F16A = (_Float16*)d_out;                           // [0, 64 MB) of d_out
  _Float16* F16B = (_Float16*)((char*)d_out + F16_IMG_BYTES);  // [64, 128 MB) of d_out

  const size_t WF_PASS = 8 * 36 * 64 * 8;

  k_wprep<<<dim3(576, 4), 256, 0, stream>>>(w_ud, w_du, w_lr, w_rl, Wf);

  if (ws_size >= WS_NEED) {
    // ---- primary: trapezoid scan, launch boundary every 8 steps ----
    _Float16* cb_[2] = {carryA, carryB};
    // P1: vertical fwd, x = d_in (f32, read-only), y = d_out (f32)
    k_carry0<float, float><<<dim3(16, B_), 256, 0, stream>>>(x, Y, carryA, H_, W_, 0);
    for (int n0 = 0, j = 0; n0 < H_ - 1; n0 += 8, ++j) {
      int ns = H_ - 1 - n0; if (ns > 8) ns = 8;
      k_scan3<float, float, 32, 6><<<dim3(8, B_), 256, 0, stream>>>(
          x, Y, Wf + 0 * WF_PASS, cb_[j & 1], cb_[(j + 1) & 1], H_, W_, n0, ns, +1, 0);
    }
    // P2: vertical bwd, x = d_out (f32), y = YtA (f16) [= old t1 quantization point]
    k_carry0<float, _Float16><<<dim3(16, B_), 256, 0, stream>>>(Y, YtA, carryA, H_, W_, H_ - 1);
    for (int n0 = 0, j = 0; n0 < H_ - 1; n0 += 8, ++j) {
      int ns = H_ - 1 - n0; if (ns > 8) ns = 8;
      k_scan3<float, _Float16, 32, 6><<<dim3(8, B_), 256, 0, stream>>>(
          Y, YtA, Wf + 1 * WF_PASS, cb_[j & 1], cb_[(j + 1) & 1], H_, W_, n0, ns, -1, H_ - 1);
    }
    // transpose YtA [b][c][h][w] -> F16A [b][c][w][h]
    k_t1h<<<dim3(8, 4, B_ * C_), dim3(32, 8), 0, stream>>>(YtA, F16A);
    // P3: horizontal fwd, x = F16A, y = YtA (transposed layout: S=W, L=H)
    k_carry0<_Float16, _Float16><<<dim3(8, B_), 256, 0, stream>>>(F16A, YtA, carryA, W_, H_, 0);
    for (int n0 = 0, j = 0; n0 < W_ - 1; n0 += 8, ++j) {
      int ns = W_ - 1 - n0; if (ns > 8) ns = 8;
      k_scan3<_Float16, _Float16, 16, 5><<<dim3(8, B_), 256, 0, stream>>>(
          F16A, YtA, Wf + 2 * WF_PASS, cb_[j & 1], cb_[(j + 1) & 1], W_, H_, n0, ns, +1, 0);
    }
    // P4: horizontal bwd, x = YtA, y = F16B
    k_carry0<_Float16, _Float16><<<dim3(8, B_), 256, 0, stream>>>(YtA, F16B, carryA, W_, H_, W_ - 1);
    for (int n0 = 0, j = 0; n0 < W_ - 1; n0 += 8, ++j) {
      int ns = W_ - 1 - n0; if (ns > 8) ns = 8;
      k_scan3<_Float16, _Float16, 16, 5><<<dim3(8, B_), 256, 0, stream>>>(
          YtA, F16B, Wf + 3 * WF_PASS, cb_[j & 1], cb_[(j + 1) & 1], W_, H_, n0, ns, -1, W_ - 1);
    }
    // move P4 result out of d_out (k_t2 will overwrite all of d_out), then back-transpose
    k_copy<<<2048, 256, 0, stream>>>((const float*)F16B, (float*)YtA, F16_IMG_BYTES / 16);
    k_t2<<<dim3(8, 4, B_ * C_), dim3(32, 8), 0, stream>>>(YtA, Y);
  } else {
    // ---- fallback: proven per-step path ----
    k_copy<<<2048, 256, 0, stream>>>(x, Y, B_ * C_ * H_ * W_ / 4);
    for (int i = 1; i < H_; ++i)
      k_step_v<<<dim3(W_ / 64, B_), 256, 0, stream>>>(Y, Wf + 0 * WF_PASS, i, i - 1);
    for (int i = H_ - 2; i >= 0; --i)
      k_step_v<<<dim3(W_ / 64, B_), 256, 0, stream>>>(Y, Wf + 1 * WF_PASS, i, i + 1);
    for (int i = 1; i < W_; ++i)
      k_step_h<<<dim3(H_ / 64, B_), 256, 0, stream>>>(Y, Wf + 2 * WF_PASS, i, i - 1);
    for (int i = W_ - 2; i >= 0; --i)
      k_step_h<<<dim3(H_ / 64, B_), 256, 0, stream>>>(Y, Wf + 3 * WF_PASS, i, i + 1);
  }
}

// Round 6
// 4922.710 us; speedup vs baseline: 3.4643x; 1.9703x over previous
//
#include <hip/hip_runtime.h>

#define C_ 128
#define KS_ 9
#define B_ 8
#define H_ 128
#define W_ 256
#define HW_ (H_ * W_)    // 32768
#define CHW_ (C_ * HW_)  // 4194304

typedef _Float16 half8 __attribute__((ext_vector_type(8)));
typedef float floatx4 __attribute__((ext_vector_type(4)));
typedef unsigned long long ull;

// f16 full image = 8*128*128*256*2 B
#define F16_IMG_BYTES 67108864u

// ws layout (primary path)
#define WS_WF_OFF    0u
#define WS_WF_BYTES  1179648u            // 4 passes * 294,912 B fragment weights
#define WS_CARRY_OFF 1183744u            // 2 x [b][col<=256][128ci] f16 = 2 x 524,288 B
#define CARRY_HALVES (8 * 256 * 128)     // 262,144 halves = 524,288 B per parity buffer
#define WS_YT_OFF    2232320u            // f16 image A: 64 MB
#define WS_NEED      (WS_YT_OFF + F16_IMG_BYTES)  // 69,341,184

__device__ __forceinline__ int imin(int a, int b) { return a < b ? a : b; }
__device__ __forceinline__ int imax(int a, int b) { return a > b ? a : b; }

// ---------------- utility kernels ----------------
__global__ void k_copy(const float* __restrict__ in, float* __restrict__ out, int n4) {
  int i = blockIdx.x * blockDim.x + threadIdx.x;
  int stride = gridDim.x * blockDim.x;
  const floatx4* ip = (const floatx4*)in;
  floatx4* op = (floatx4*)out;
  for (; i < n4; i += stride) op[i] = ip[i];
}

// weight prep: fp32 [co][ci][kk] -> f16 A-fragment order
// idx = (((mt8)*36 + ks)*64 + lane)*8 + j ; co = mt8*16 + (lane&15); k = ks*32 + q*8 + j
__global__ void k_wprep(const float* w0, const float* w1, const float* w2, const float* w3,
                        _Float16* __restrict__ wf) {
  const float* Wp[4] = {w0, w1, w2, w3};
  const float* W = Wp[blockIdx.y];
  _Float16* out = wf + (size_t)blockIdx.y * (8 * 36 * 64 * 8);
  int idx = blockIdx.x * 256 + threadIdx.x;
  if (idx >= 8 * 36 * 64 * 8) return;
  int j = idx & 7;
  int lane = (idx >> 3) & 63;
  int ks = (idx >> 9) % 36;
  int mt = (idx >> 9) / 36;
  int co = mt * 16 + (lane & 15);
  int k = ks * 32 + ((lane >> 4) & 3) * 8 + j;
  int kk = k >> 7, ci = k & 127;
  out[idx] = (_Float16)W[((size_t)co * C_ + ci) * KS_ + kk];
}

// initial carry row for a pass: cout[b][col][ci] = (f16) imgX[b][ci][istart][col]
// also writes imgY row istart (y[0] = x[0]).
template <typename XT, typename YT>
__global__ void k_carry0(const XT* __restrict__ imgX, YT* __restrict__ imgY,
                         _Float16* __restrict__ cout_, int S, int L, int istart) {
  int b = blockIdx.y;
  int e = blockIdx.x * 256 + threadIdx.x;  // (col, ci-group-of-8)
  if (e >= L * 16) return;
  int col = e >> 4, ci0 = (e & 15) * 8;
  union { ull u[2]; _Float16 h[8]; } pk;
#pragma unroll
  for (int u2 = 0; u2 < 8; ++u2) {
    size_t off = ((size_t)(b * C_ + ci0 + u2) * S + istart) * L + col;
    float v = (float)imgX[off];
    pk.h[u2] = (_Float16)v;
    imgY[off] = (YT)v;
  }
  ull* dst = (ull*)(cout_ + ((size_t)b * L + col) * 128 + ci0);
  dst[0] = pk.u[0];
  dst[1] = pk.u[1];
}

// transpose f16 [b][c][h][w] -> f16 [b][c][w][h]
__global__ void k_t1h(const _Float16* __restrict__ in, _Float16* __restrict__ out) {
  __shared__ _Float16 tile[32][33];
  size_t pbase = (size_t)blockIdx.z * HW_;
  int h0 = blockIdx.y * 32, w0 = blockIdx.x * 32;
  int tx = threadIdx.x, ty = threadIdx.y;
  for (int i = 0; i < 32; i += 8)
    tile[ty + i][tx] = in[pbase + (size_t)(h0 + ty + i) * W_ + (w0 + tx)];
  __syncthreads();
  for (int i = 0; i < 32; i += 8)
    out[pbase + (size_t)(w0 + ty + i) * H_ + (h0 + tx)] = tile[tx][ty + i];
}

// transpose f16 [b][c][w][h] -> fp32 NCHW
__global__ void k_t2(const _Float16* __restrict__ in, float* __restrict__ out) {
  __shared__ float tile[32][33];
  size_t pbase = (size_t)blockIdx.z * HW_;
  int h0 = blockIdx.y * 32, w0 = blockIdx.x * 32;
  int tx = threadIdx.x, ty = threadIdx.y;
  for (int i = 0; i < 32; i += 8)
    tile[ty + i][tx] = (float)in[pbase + (size_t)(w0 + ty + i) * H_ + (h0 + tx)];
  __syncthreads();
  for (int i = 0; i < 32; i += 8)
    out[pbase + (size_t)(h0 + ty + i) * W_ + (w0 + tx)] = tile[tx][ty + i];
}

// ---------------- trapezoid scan kernel: P=8 steps per launch, no cross-WG sync --------------
// 8 waves (512 thr), wave w owns m-tile w (co = w*16..w*16+16): per-wave A-frag = 144 VGPR
// -> 2 waves/SIMD resident (vs 1 with 2 m-tiles/wave). All waves process all tiles of the
// step (balanced). Carry lives in LDS (double-buffered); halo ext = 32-4p computed
// redundantly (bitwise-identical across WGs). imgX READ-ONLY, imgY WRITE-ONLY (own strip);
// cin/cout distinct parity buffers; launch boundary is the only synchronization.
template <typename XT, typename YT, int WC, int MAXT>
__global__ __launch_bounds__(512, 2) void k_scan3(
    const XT* __restrict__ imgX, YT* __restrict__ imgY,
    const _Float16* __restrict__ Wf, const _Float16* __restrict__ cin,
    _Float16* __restrict__ cout_,
    int S, int L, int n0, int nsteps, int dir, int istart) {
  constexpr int MAXW = WC + 72;        // cols [c0-36, c0+WC+36); 4-col zero guards each side
  constexpr int BSZ = MAXW * 132;      // row stride 132 halves (8B-aligned, conflict-light)
  __shared__ _Float16 Bl[2][BSZ];
  const int c0 = blockIdx.x * WC;
  const int b = blockIdx.y;
  const int t = threadIdx.x;
  const int lane = t & 63, wave = t >> 6;  // wave 0..7 = m-tile index
  const int q = lane >> 4, m = lane & 15;

  // A-fragments: wave w owns m-tile w: 36 half8 (144 VGPRs)
  half8 A_[36];
  {
    const half8* wp2 = (const half8*)Wf;
#pragma unroll
    for (int ks = 0; ks < 36; ++ks)
      A_[ks] = wp2[(wave * 36 + ks) * 64 + lane];
  }

  // zero both LDS buffers (conv zero-padding guards); slots of 8 halves = 2 ull stores
  for (int i = t * 8; i < BSZ; i += 4096) {
    ull* z0 = (ull*)(&Bl[0][i]);
    ull* z1 = (ull*)(&Bl[1][i]);
    z0[0] = 0ull; z0[1] = 0ull;
    z1[0] = 0ull; z1[1] = 0ull;
  }
  __syncthreads();

  // load carry row n0: cols [c0-32, c0+WC+32) ∩ [0,L) into Bl[0]
  {
    const int NCH = (WC + 64) * 16;
    for (int e = t; e < NCH; e += 512) {
      const int lcol = e >> 4;
      const int col = c0 - 32 + lcol;
      if (col >= 0 && col < L) {
        const int ci0 = (e & 15) * 8;
        const ull* src = (const ull*)(cin + ((size_t)b * L + col) * 128 + ci0);
        ull* dst = (ull*)(&Bl[0][(lcol + 4) * 132 + ci0]);
        dst[0] = src[0];
        dst[1] = src[1];
      }
    }
  }
  __syncthreads();

  int cur = 0;
  for (int p = 1; p <= nsteps; ++p) {
    const int row = istart + dir * (n0 + p);
    const int ext = 32 - 4 * p;  // valid halo width this step
    const int lo = imax(c0 - ext, 0);
    const int hi = imin(c0 + WC + ext, L);
    const int tt0 = -((c0 - lo + 15) >> 4);
    const int ntile = ((hi - c0 + 15) >> 4) - tt0;
    const _Float16* BR = Bl[cur];
    _Float16* BW = Bl[cur ^ 1];
    const size_t rbase = ((size_t)(b * C_ + wave * 16) * S + row) * L;

    // issue ALL tiles' x-loads up front (pass-input, independent of the scan)
    float xv[MAXT][4];
#pragma unroll
    for (int u = 0; u < MAXT; ++u) {
      if (u >= ntile) break;
      const int col = c0 + (tt0 + u) * 16 + m;
      const bool ld2 = (col >= lo) && (col < hi);
#pragma unroll
      for (int r = 0; r < 4; ++r)
        xv[u][r] = ld2 ? (float)imgX[rbase + (size_t)(q * 4 + r) * (S * L) + col] : 0.f;
    }

#pragma unroll
    for (int u = 0; u < MAXT; ++u) {
      if (u >= ntile) break;
      const int ti = tt0 + u;
      // GEMM: 16 co x 1152 K x 16 cols; dual acc chains (even/odd ks) for ILP
      floatx4 aA = {0.f, 0.f, 0.f, 0.f}, aB = {0.f, 0.f, 0.f, 0.f};
      const int lbase = ti * 16 + m + 32;  // lcol for kk=0 tap (col + kk - 4 -> +36-4)
#pragma unroll
      for (int ks2 = 0; ks2 < 18; ++ks2) {
        const int ksA = 2 * ks2, ksB = 2 * ks2 + 1;
        {
          const int kk = ksA >> 2, ci0 = (ksA & 3) * 32 + q * 8;
          // 132-half row stride is only 8B-aligned: 2x ull (ds_read_b64), not half8
          const ull* bp = (const ull*)(BR + (lbase + kk) * 132 + ci0);
          union { ull u2[2]; half8 v; } bf;
          bf.u2[0] = bp[0]; bf.u2[1] = bp[1];
          aA = __builtin_amdgcn_mfma_f32_16x16x32_f16(A_[ksA], bf.v, aA, 0, 0, 0);
        }
        {
          const int kk = ksB >> 2, ci0 = (ksB & 3) * 32 + q * 8;
          const ull* bp = (const ull*)(BR + (lbase + kk) * 132 + ci0);
          union { ull u2[2]; half8 v; } bf;
          bf.u2[0] = bp[0]; bf.u2[1] = bp[1];
          aB = __builtin_amdgcn_mfma_f32_16x16x32_f16(A_[ksB], bf.v, aB, 0, 0, 0);
        }
      }
      // epilogue: y = x + relu(conv); img store (own strip) + LDS store (valid range)
      const int col = c0 + ti * 16 + m;
      const bool instrip = (col >= c0) && (col < c0 + WC);
      const bool inlds = (col >= lo) && (col < hi);
      union { ull uu; _Float16 h[4]; } pk;
#pragma unroll
      for (int r = 0; r < 4; ++r) {
        const float y = xv[u][r] + fmaxf(aA[r] + aB[r], 0.f);
        pk.h[r] = (_Float16)y;
        if (instrip)
          imgY[rbase + (size_t)(q * 4 + r) * (S * L) + col] = (YT)y;
      }
      if (inlds)
        *(ull*)(BW + (col - c0 + 36) * 132 + wave * 16 + q * 4) = pk.uu;
    }
    __syncthreads();  // one barrier per step: BW complete before it becomes BR
    cur ^= 1;
  }

  // publish own strip's carry (row n0+nsteps); each (lc, ci-group) = 8 halves = 2 ull
  {
    const _Float16* BP = Bl[cur];
    for (int e = t; e < WC * 16; e += 512) {
      const int lc = e >> 4, ci0 = (e & 15) * 8;
      ull* dst = (ull*)(cout_ + ((size_t)b * L + (c0 + lc)) * 128 + ci0);
      const ull* src = (const ull*)(BP + (lc + 36) * 132 + ci0);
      dst[0] = src[0];
      dst[1] = src[1];
    }
  }
}

// ---------------- fallback path (round-2, proven): per-step kernels ----------------
__device__ __forceinline__ void gemm_acc_fb(const _Float16* Bl, const _Float16* __restrict__ Wfrag,
                                            int wrow_base, int lane, floatx4* acc) {
  const int q = lane >> 4;
  const half8* wfp = (const half8*)Wfrag + lane;
  for (int ks = 0; ks < 36; ++ks) {
    int k0 = ks * 32 + q * 8;
    int kk = k0 >> 7;
    int ci0 = k0 & 127;
    half8 bf = *(const half8*)&Bl[(size_t)(wrow_base + kk) * C_ + ci0];
    const half8* wp = wfp + ks * 64;
#pragma unroll
    for (int mt = 0; mt < 8; ++mt)
      acc[mt] = __builtin_amdgcn_mfma_f32_16x16x32_f16(wp[mt * 36 * 64], bf, acc[mt], 0, 0, 0);
  }
}

__global__ __launch_bounds__(256) void k_step_v(float* __restrict__ Y,
                                                const _Float16* __restrict__ Wfrag,
                                                int row, int prev) {
  __shared__ _Float16 Bl[80 * 128];
  const int b = blockIdx.y, w0 = blockIdx.x * 64, t = threadIdx.x;
  {
    const float* base = Y + (size_t)b * CHW_ + (size_t)prev * W_;
#pragma unroll
    for (int it = 0; it < 10; ++it) {
      int c = it * 256 + t;
      int ci = c / 20, c4 = c % 20;
      int wst = w0 - 8 + c4 * 4;
      const float* p = base + (size_t)ci * HW_ + wst;
      float v[4];
      if (wst >= 0 && wst + 4 <= W_) {
        floatx4 u = *(const floatx4*)p;
        v[0] = u[0]; v[1] = u[1]; v[2] = u[2]; v[3] = u[3];
      } else {
#pragma unroll
        for (int j = 0; j < 4; ++j) { int w = wst + j; v[j] = (w >= 0 && w < W_) ? p[j] : 0.f; }
      }
      int wl = c4 * 4;
#pragma unroll
      for (int j = 0; j < 4; ++j) Bl[(wl + j) * C_ + ci] = (_Float16)v[j];
    }
  }
  __syncthreads();
  const int lane = t & 63, wave = t >> 6, q = lane >> 4, l15 = lane & 15;
  floatx4 acc[8];
#pragma unroll
  for (int mt = 0; mt < 8; ++mt) acc[mt] = (floatx4){0.f, 0.f, 0.f, 0.f};
  gemm_acc_fb(Bl, Wfrag, wave * 16 + l15 + 4, lane, acc);
  const int wcol = w0 + wave * 16 + l15;
#pragma unroll
  for (int mt = 0; mt < 8; ++mt)
#pragma unroll
    for (int r = 0; r < 4; ++r) {
      int co = mt * 16 + q * 4 + r;
      size_t off = (size_t)b * CHW_ + (size_t)co * HW_ + (size_t)row * W_ + wcol;
      Y[off] = Y[off] + fmaxf(acc[mt][r], 0.f);
    }
}

__global__ __launch_bounds__(256) void k_step_h(float* __restrict__ Y,
                                                const _Float16* __restrict__ Wfrag,
                                                int row, int prev) {
  __shared__ _Float16 Bl[80 * 128];
  const int b = blockIdx.y, h0 = blockIdx.x * 64, t = threadIdx.x;
  {
    const float* base = Y + (size_t)b * CHW_ + prev;
    for (int e = t; e < 80 * 128; e += 256) {
      int hl = e >> 7, ci = e & 127, h = h0 - 8 + hl;
      float v = 0.f;
      if (h >= 0 && h < H_) v = base[(size_t)ci * HW_ + (size_t)h * W_];
      Bl[hl * C_ + ci] = (_Float16)v;
    }
  }
  __syncthreads();
  const int lane = t & 63, wave = t >> 6, q = lane >> 4, l15 = lane & 15;
  floatx4 acc[8];
#pragma unroll
  for (int mt = 0; mt < 8; ++mt) acc[mt] = (floatx4){0.f, 0.f, 0.f, 0.f};
  gemm_acc_fb(Bl, Wfrag, wave * 16 + l15 + 4, lane, acc);
  const int hc = h0 + wave * 16 + l15;
#pragma unroll
  for (int mt = 0; mt < 8; ++mt)
#pragma unroll
    for (int r = 0; r < 4; ++r) {
      int co = mt * 16 + q * 4 + r;
      size_t off = (size_t)b * CHW_ + (size_t)co * HW_ + (size_t)hc * W_ + row;
      Y[off] = Y[off] + fmaxf(acc[mt][r], 0.f);
    }
}

extern "C" void kernel_launch(void* const* d_in, const int* in_sizes, int n_in,
                              void* d_out, int out_size, void* d_ws, size_t ws_size,
                              hipStream_t stream) {
  const float* x = (const float*)d_in[0];
  const float* w_ud = (const float*)d_in[1];
  const float* w_du = (const float*)d_in[2];
  const float* w_lr = (const float*)d_in[3];
  const float* w_rl = (const float*)d_in[4];

  float* Y = (float*)d_out;  // f32 image (P1 out / P2 in); scratch later
  char* ws = (char*)d_ws;
  _Float16* Wf = (_Float16*)(ws + WS_WF_OFF);
  _Float16* carryA = (_Float16*)(ws + WS_CARRY_OFF);          // parity 0
  _Float16* carryB = carryA + CARRY_HALVES;                    // parity 1
  _Float16* YtA = (_Float16*)(ws + WS_YT_OFF);                 // 64 MB f16 image (ws)
  _Float16* F16A = (_Float16*)d_out;                           // [0, 64 MB) of d_out
  _Float16* F16B = (_Float16*)((char*)d_out + F16_IMG_BYTES);  // [64, 128 MB) of d_out

  const size_t WF_PASS = 8 * 36 * 64 * 8;

  k_wprep<<<dim3(576, 4), 256, 0, stream>>>(w_ud, w_du, w_lr, w_rl, Wf);

  if (ws_size >= WS_NEED) {
    // ---- primary: trapezoid scan, launch boundary every 8 steps, 16 strips, 8 waves ----
    _Float16* cb_[2] = {carryA, carryB};
    // P1: vertical fwd, x = d_in (f32, read-only), y = d_out (f32)
    k_carry0<float, float><<<dim3(16, B_), 256, 0, stream>>>(x, Y, carryA, H_, W_, 0);
    for (int n0 = 0, j = 0; n0 < H_ - 1; n0 += 8, ++j) {
      int ns = H_ - 1 - n0; if (ns > 8) ns = 8;
      k_scan3<float, float, 16, 5><<<dim3(16, B_), 512, 0, stream>>>(
          x, Y, Wf + 0 * WF_PASS, cb_[j & 1], cb_[(j + 1) & 1], H_, W_, n0, ns, +1, 0);
    }
    // P2: vertical bwd, x = d_out (f32), y = YtA (f16) [= old t1 quantization point]
    k_carry0<float, _Float16><<<dim3(16, B_), 256, 0, stream>>>(Y, YtA, carryA, H_, W_, H_ - 1);
    for (int n0 = 0, j = 0; n0 < H_ - 1; n0 += 8, ++j) {
      int ns = H_ - 1 - n0; if (ns > 8) ns = 8;
      k_scan3<float, _Float16, 16, 5><<<dim3(16, B_), 512, 0, stream>>>(
          Y, YtA, Wf + 1 * WF_PASS, cb_[j & 1], cb_[(j + 1) & 1], H_, W_, n0, ns, -1, H_ - 1);
    }
    // transpose YtA [b][c][h][w] -> F16A [b][c][w][h]
    k_t1h<<<dim3(8, 4, B_ * C_), dim3(32, 8), 0, stream>>>(YtA, F16A);
    // P3: horizontal fwd, x = F16A, y = YtA (transposed layout: S=W, L=H)
    k_carry0<_Float16, _Float16><<<dim3(8, B_), 256, 0, stream>>>(F16A, YtA, carryA, W_, H_, 0);
    for (int n0 = 0, j = 0; n0 < W_ - 1; n0 += 8, ++j) {
      int ns = W_ - 1 - n0; if (ns > 8) ns = 8;
      k_scan3<_Float16, _Float16, 8, 5><<<dim3(16, B_), 512, 0, stream>>>(
          F16A, YtA, Wf + 2 * WF_PASS, cb_[j & 1], cb_[(j + 1) & 1], W_, H_, n0, ns, +1, 0);
    }
    // P4: horizontal bwd, x = YtA, y = F16B
    k_carry0<_Float16, _Float16><<<dim3(8, B_), 256, 0, stream>>>(YtA, F16B, carryA, W_, H_, W_ - 1);
    for (int n0 = 0, j = 0; n0 < W_ - 1; n0 += 8, ++j) {
      int ns = W_ - 1 - n0; if (ns > 8) ns = 8;
      k_scan3<_Float16, _Float16, 8, 5><<<dim3(16, B_), 512, 0, stream>>>(
          YtA, F16B, Wf + 3 * WF_PASS, cb_[j & 1], cb_[(j + 1) & 1], W_, H_, n0, ns, -1, W_ - 1);
    }
    // move P4 result out of d_out (k_t2 will overwrite all of d_out), then back-transpose
    k_copy<<<2048, 256, 0, stream>>>((const float*)F16B, (float*)YtA, F16_IMG_BYTES / 16);
    k_t2<<<dim3(8, 4, B_ * C_), dim3(32, 8), 0, stream>>>(YtA, Y);
  } else {
    // ---- fallback: proven per-step path ----
    k_copy<<<2048, 256, 0, stream>>>(x, Y, B_ * C_ * H_ * W_ / 4);
    for (int i = 1; i < H_; ++i)
      k_step_v<<<dim3(W_ / 64, B_), 256, 0, stream>>>(Y, Wf + 0 * WF_PASS, i, i - 1);
    for (int i = H_ - 2; i >= 0; --i)
      k_step_v<<<dim3(W_ / 64, B_), 256, 0, stream>>>(Y, Wf + 1 * WF_PASS, i, i + 1);
    for (int i = 1; i < W_; ++i)
      k_step_h<<<dim3(H_ / 64, B_), 256, 0, stream>>>(Y, Wf + 2 * WF_PASS, i, i - 1);
    for (int i = W_ - 2; i >= 0; --i)
      k_step_h<<<dim3(H_ / 64, B_), 256, 0, stream>>>(Y, Wf + 3 * WF_PASS, i, i + 1);
  }
}

// Round 7
// 4215.446 us; speedup vs baseline: 4.0456x; 1.1678x over previous
//
#include <hip/hip_runtime.h>

#define C_ 128
#define KS_ 9
#define B_ 8
#define H_ 128
#define W_ 256
#define HW_ (H_ * W_)    // 32768
#define CHW_ (C_ * HW_)  // 4194304

typedef _Float16 half8 __attribute__((ext_vector_type(8)));
typedef float floatx4 __attribute__((ext_vector_type(4)));
typedef unsigned long long ull;

// f16 full image = 8*128*128*256*2 B
#define F16_IMG_BYTES 67108864u

// ws layout (primary path)
#define WS_WF_OFF    0u
#define WS_WF_BYTES  1179648u            // 4 passes * 294,912 B fragment weights
#define WS_CARRY_OFF 1183744u            // 2 x [b][col<=256][128ci] f16 = 2 x 524,288 B
#define CARRY_HALVES (8 * 256 * 128)     // 262,144 halves = 524,288 B per parity buffer
#define WS_YT_OFF    2232320u            // f16 image A: 64 MB
#define WS_NEED      (WS_YT_OFF + F16_IMG_BYTES)  // 69,341,184

__device__ __forceinline__ int imin(int a, int b) { return a < b ? a : b; }
__device__ __forceinline__ int imax(int a, int b) { return a > b ? a : b; }

// ---------------- utility kernels ----------------
__global__ void k_copy(const float* __restrict__ in, float* __restrict__ out, int n4) {
  int i = blockIdx.x * blockDim.x + threadIdx.x;
  int stride = gridDim.x * blockDim.x;
  const floatx4* ip = (const floatx4*)in;
  floatx4* op = (floatx4*)out;
  for (; i < n4; i += stride) op[i] = ip[i];
}

// weight prep: fp32 [co][ci][kk] -> f16 A-fragment order
// idx = (((mt8)*36 + ks)*64 + lane)*8 + j ; co = mt8*16 + (lane&15); k = ks*32 + q*8 + j
__global__ void k_wprep(const float* w0, const float* w1, const float* w2, const float* w3,
                        _Float16* __restrict__ wf) {
  const float* Wp[4] = {w0, w1, w2, w3};
  const float* W = Wp[blockIdx.y];
  _Float16* out = wf + (size_t)blockIdx.y * (8 * 36 * 64 * 8);
  int idx = blockIdx.x * 256 + threadIdx.x;
  if (idx >= 8 * 36 * 64 * 8) return;
  int j = idx & 7;
  int lane = (idx >> 3) & 63;
  int ks = (idx >> 9) % 36;
  int mt = (idx >> 9) / 36;
  int co = mt * 16 + (lane & 15);
  int k = ks * 32 + ((lane >> 4) & 3) * 8 + j;
  int kk = k >> 7, ci = k & 127;
  out[idx] = (_Float16)W[((size_t)co * C_ + ci) * KS_ + kk];
}

// initial carry row for a pass: cout[b][col][ci] = (f16) imgX[b][ci][istart][col]
// also writes imgY row istart (y[0] = x[0]).
template <typename XT, typename YT>
__global__ void k_carry0(const XT* __restrict__ imgX, YT* __restrict__ imgY,
                         _Float16* __restrict__ cout_, int S, int L, int istart) {
  int b = blockIdx.y;
  int e = blockIdx.x * 256 + threadIdx.x;  // (col, ci-group-of-8)
  if (e >= L * 16) return;
  int col = e >> 4, ci0 = (e & 15) * 8;
  union { ull u[2]; _Float16 h[8]; } pk;
#pragma unroll
  for (int u2 = 0; u2 < 8; ++u2) {
    size_t off = ((size_t)(b * C_ + ci0 + u2) * S + istart) * L + col;
    float v = (float)imgX[off];
    pk.h[u2] = (_Float16)v;
    imgY[off] = (YT)v;
  }
  ull* dst = (ull*)(cout_ + ((size_t)b * L + col) * 128 + ci0);
  dst[0] = pk.u[0];
  dst[1] = pk.u[1];
}

// transpose f16 [b][c][h][w] -> f16 [b][c][w][h]
__global__ void k_t1h(const _Float16* __restrict__ in, _Float16* __restrict__ out) {
  __shared__ _Float16 tile[32][33];
  size_t pbase = (size_t)blockIdx.z * HW_;
  int h0 = blockIdx.y * 32, w0 = blockIdx.x * 32;
  int tx = threadIdx.x, ty = threadIdx.y;
  for (int i = 0; i < 32; i += 8)
    tile[ty + i][tx] = in[pbase + (size_t)(h0 + ty + i) * W_ + (w0 + tx)];
  __syncthreads();
  for (int i = 0; i < 32; i += 8)
    out[pbase + (size_t)(w0 + ty + i) * H_ + (h0 + tx)] = tile[tx][ty + i];
}

// transpose f16 [b][c][w][h] -> fp32 NCHW
__global__ void k_t2(const _Float16* __restrict__ in, float* __restrict__ out) {
  __shared__ float tile[32][33];
  size_t pbase = (size_t)blockIdx.z * HW_;
  int h0 = blockIdx.y * 32, w0 = blockIdx.x * 32;
  int tx = threadIdx.x, ty = threadIdx.y;
  for (int i = 0; i < 32; i += 8)
    tile[ty + i][tx] = (float)in[pbase + (size_t)(w0 + ty + i) * H_ + (h0 + tx)];
  __syncthreads();
  for (int i = 0; i < 32; i += 8)
    out[pbase + (size_t)(h0 + ty + i) * W_ + (w0 + tx)] = tile[tx][ty + i];
}

// ---------------- trapezoid scan kernel: P=8 steps per launch, no cross-WG sync --------------
// 8 waves (512 thr). Wave-pair K-split: pair g = wave>>1 owns m-tiles {2g,2g+1} (co 32);
// within a pair, wave h = wave&1 computes K-half h (18 of 36 ks). Each B fragment read
// feeds TWO MFMAs (m-tile 2g and 2g+1) -> per-CU LDS B-traffic halves vs 1-mtile/wave.
// Partials exchanged via Sc[] LDS scratch (+1 barrier per tile). Epilogue m-tile =
// 2g+h = wave, so epilogue/carry/x-load mapping is unchanged from the proven version.
// A-frag budget stays 144 VGPR/wave -> 2 waves/SIMD.
template <typename XT, typename YT, int WC, int MAXT>
__global__ __launch_bounds__(512, 2) void k_scan3(
    const XT* __restrict__ imgX, YT* __restrict__ imgY,
    const _Float16* __restrict__ Wf, const _Float16* __restrict__ cin,
    _Float16* __restrict__ cout_,
    int S, int L, int n0, int nsteps, int dir, int istart) {
  constexpr int MAXW = WC + 72;        // cols [c0-36, c0+WC+36); 4-col zero guards each side
  constexpr int BSZ = MAXW * 132;      // row stride 132 halves (8B-aligned, conflict-light)
  __shared__ _Float16 Bl[2][BSZ];
  __shared__ floatx4 Sc[2][8][64];     // per-tile partial-sum exchange (dbuf by tile parity)
  const int c0 = blockIdx.x * WC;
  const int b = blockIdx.y;
  const int t = threadIdx.x;
  const int lane = t & 63, wave = t >> 6;
  const int q = lane >> 4, m = lane & 15;
  const int h = wave & 1;              // K-half
  const int g = wave >> 1;             // co-pair group (m-tiles 2g, 2g+1)

  // A-fragments: m-tiles {2g, 2g+1}, K-half h (ks = h*18 + i): 36 half8 = 144 VGPRs
  half8 A0[18], A1[18];
  {
    const half8* wp2 = (const half8*)Wf;
#pragma unroll
    for (int i = 0; i < 18; ++i) {
      A0[i] = wp2[((g * 2 + 0) * 36 + h * 18 + i) * 64 + lane];
      A1[i] = wp2[((g * 2 + 1) * 36 + h * 18 + i) * 64 + lane];
    }
  }

  // zero both LDS buffers (conv zero-padding guards); slots of 8 halves = 2 ull stores
  for (int i = t * 8; i < BSZ; i += 4096) {
    ull* z0 = (ull*)(&Bl[0][i]);
    ull* z1 = (ull*)(&Bl[1][i]);
    z0[0] = 0ull; z0[1] = 0ull;
    z1[0] = 0ull; z1[1] = 0ull;
  }
  __syncthreads();

  // load carry row n0: cols [c0-32, c0+WC+32) ∩ [0,L) into Bl[0]
  {
    const int NCH = (WC + 64) * 16;
    for (int e = t; e < NCH; e += 512) {
      const int lcol = e >> 4;
      const int col = c0 - 32 + lcol;
      if (col >= 0 && col < L) {
        const int ci0 = (e & 15) * 8;
        const ull* src = (const ull*)(cin + ((size_t)b * L + col) * 128 + ci0);
        ull* dst = (ull*)(&Bl[0][(lcol + 4) * 132 + ci0]);
        dst[0] = src[0];
        dst[1] = src[1];
      }
    }
  }
  __syncthreads();

  int cur = 0;
  for (int p = 1; p <= nsteps; ++p) {
    const int row = istart + dir * (n0 + p);
    const int ext = 32 - 4 * p;  // valid halo width this step
    const int lo = imax(c0 - ext, 0);
    const int hi = imin(c0 + WC + ext, L);
    const int tt0 = -((c0 - lo + 15) >> 4);
    const int ntile = ((hi - c0 + 15) >> 4) - tt0;
    const _Float16* BR = Bl[cur];
    _Float16* BW = Bl[cur ^ 1];
    const size_t rbase = ((size_t)(b * C_ + wave * 16) * S + row) * L;  // epilogue mt = wave

    // issue ALL tiles' x-loads up front (pass-input, independent of the scan)
    float xv[MAXT][4];
#pragma unroll
    for (int u = 0; u < MAXT; ++u) {
      if (u >= ntile) break;
      const int col = c0 + (tt0 + u) * 16 + m;
      const bool ld2 = (col >= lo) && (col < hi);
#pragma unroll
      for (int r = 0; r < 4; ++r)
        xv[u][r] = ld2 ? (float)imgX[rbase + (size_t)(q * 4 + r) * (S * L) + col] : 0.f;
    }

#pragma unroll
    for (int u = 0; u < MAXT; ++u) {
      if (u >= ntile) break;  // uniform per-WG trip count
      const int ti = tt0 + u;
      // GEMM: m-tiles {2g,2g+1} x K-half h x 16 cols; each B read feeds both m-tiles
      floatx4 aA = {0.f, 0.f, 0.f, 0.f}, aB = {0.f, 0.f, 0.f, 0.f};
      const int lbase = ti * 16 + m + 32;  // lcol for kk=0 tap (col + kk - 4 -> +36-4)
#pragma unroll
      for (int i = 0; i < 18; ++i) {
        const int ks = h * 18 + i;
        const int kk = ks >> 2;
        const int ci0 = (ks & 3) * 32 + q * 8;
        // 132-half row stride is only 8B-aligned: 2x ull (ds_read_b64), not half8
        const ull* bp = (const ull*)(BR + (lbase + kk) * 132 + ci0);
        union { ull u2[2]; half8 v; } bf;
        bf.u2[0] = bp[0]; bf.u2[1] = bp[1];
        aA = __builtin_amdgcn_mfma_f32_16x16x32_f16(A0[i], bf.v, aA, 0, 0, 0);
        aB = __builtin_amdgcn_mfma_f32_16x16x32_f16(A1[i], bf.v, aB, 0, 0, 0);
      }
      // exchange partner partial: wave epilogues m-tile 2g+h -> own acc (h?aB:aA);
      // give partner the other acc; read partner's matching half and combine.
      Sc[u & 1][wave][lane] = h ? aA : aB;
      __syncthreads();
      const floatx4 ac = (h ? aB : aA) + Sc[u & 1][wave ^ 1][lane];
      // epilogue: y = x + relu(conv); img store (own strip) + LDS store (valid range)
      const int col = c0 + ti * 16 + m;
      const bool instrip = (col >= c0) && (col < c0 + WC);
      const bool inlds = (col >= lo) && (col < hi);
      union { ull uu; _Float16 h4[4]; } pk;
#pragma unroll
      for (int r = 0; r < 4; ++r) {
        const float y = xv[u][r] + fmaxf(ac[r], 0.f);
        pk.h4[r] = (_Float16)y;
        if (instrip)
          imgY[rbase + (size_t)(q * 4 + r) * (S * L) + col] = (YT)y;
      }
      if (inlds)
        *(ull*)(BW + (col - c0 + 36) * 132 + wave * 16 + q * 4) = pk.uu;
    }
    __syncthreads();  // step barrier: BW complete before it becomes BR
    cur ^= 1;
  }

  // publish own strip's carry (row n0+nsteps); each (lc, ci-group) = 8 halves = 2 ull
  {
    const _Float16* BP = Bl[cur];
    for (int e = t; e < WC * 16; e += 512) {
      const int lc = e >> 4, ci0 = (e & 15) * 8;
      ull* dst = (ull*)(cout_ + ((size_t)b * L + (c0 + lc)) * 128 + ci0);
      const ull* src = (const ull*)(BP + (lc + 36) * 132 + ci0);
      dst[0] = src[0];
      dst[1] = src[1];
    }
  }
}

// ---------------- fallback path (round-2, proven): per-step kernels ----------------
__device__ __forceinline__ void gemm_acc_fb(const _Float16* Bl, const _Float16* __restrict__ Wfrag,
                                            int wrow_base, int lane, floatx4* acc) {
  const int q = lane >> 4;
  const half8* wfp = (const half8*)Wfrag + lane;
  for (int ks = 0; ks < 36; ++ks) {
    int k0 = ks * 32 + q * 8;
    int kk = k0 >> 7;
    int ci0 = k0 & 127;
    half8 bf = *(const half8*)&Bl[(size_t)(wrow_base + kk) * C_ + ci0];
    const half8* wp = wfp + ks * 64;
#pragma unroll
    for (int mt = 0; mt < 8; ++mt)
      acc[mt] = __builtin_amdgcn_mfma_f32_16x16x32_f16(wp[mt * 36 * 64], bf, acc[mt], 0, 0, 0);
  }
}

__global__ __launch_bounds__(256) void k_step_v(float* __restrict__ Y,
                                                const _Float16* __restrict__ Wfrag,
                                                int row, int prev) {
  __shared__ _Float16 Bl[80 * 128];
  const int b = blockIdx.y, w0 = blockIdx.x * 64, t = threadIdx.x;
  {
    const float* base = Y + (size_t)b * CHW_ + (size_t)prev * W_;
#pragma unroll
    for (int it = 0; it < 10; ++it) {
      int c = it * 256 + t;
      int ci = c / 20, c4 = c % 20;
      int wst = w0 - 8 + c4 * 4;
      const float* p = base + (size_t)ci * HW_ + wst;
      float v[4];
      if (wst >= 0 && wst + 4 <= W_) {
        floatx4 u = *(const floatx4*)p;
        v[0] = u[0]; v[1] = u[1]; v[2] = u[2]; v[3] = u[3];
      } else {
#pragma unroll
        for (int j = 0; j < 4; ++j) { int w = wst + j; v[j] = (w >= 0 && w < W_) ? p[j] : 0.f; }
      }
      int wl = c4 * 4;
#pragma unroll
      for (int j = 0; j < 4; ++j) Bl[(wl + j) * C_ + ci] = (_Float16)v[j];
    }
  }
  __syncthreads();
  const int lane = t & 63, wave = t >> 6, q = lane >> 4, l15 = lane & 15;
  floatx4 acc[8];
#pragma unroll
  for (int mt = 0; mt < 8; ++mt) acc[mt] = (floatx4){0.f, 0.f, 0.f, 0.f};
  gemm_acc_fb(Bl, Wfrag, wave * 16 + l15 + 4, lane, acc);
  const int wcol = w0 + wave * 16 + l15;
#pragma unroll
  for (int mt = 0; mt < 8; ++mt)
#pragma unroll
    for (int r = 0; r < 4; ++r) {
      int co = mt * 16 + q * 4 + r;
      size_t off = (size_t)b * CHW_ + (size_t)co * HW_ + (size_t)row * W_ + wcol;
      Y[off] = Y[off] + fmaxf(acc[mt][r], 0.f);
    }
}

__global__ __launch_bounds__(256) void k_step_h(float* __restrict__ Y,
                                                const _Float16* __restrict__ Wfrag,
                                                int row, int prev) {
  __shared__ _Float16 Bl[80 * 128];
  const int b = blockIdx.y, h0 = blockIdx.x * 64, t = threadIdx.x;
  {
    const float* base = Y + (size_t)b * CHW_ + prev;
    for (int e = t; e < 80 * 128; e += 256) {
      int hl = e >> 7, ci = e & 127, h = h0 - 8 + hl;
      float v = 0.f;
      if (h >= 0 && h < H_) v = base[(size_t)ci * HW_ + (size_t)h * W_];
      Bl[hl * C_ + ci] = (_Float16)v;
    }
  }
  __syncthreads();
  const int lane = t & 63, wave = t >> 6, q = lane >> 4, l15 = lane & 15;
  floatx4 acc[8];
#pragma unroll
  for (int mt = 0; mt < 8; ++mt) acc[mt] = (floatx4){0.f, 0.f, 0.f, 0.f};
  gemm_acc_fb(Bl, Wfrag, wave * 16 + l15 + 4, lane, acc);
  const int hc = h0 + wave * 16 + l15;
#pragma unroll
  for (int mt = 0; mt < 8; ++mt)
#pragma unroll
    for (int r = 0; r < 4; ++r) {
      int co = mt * 16 + q * 4 + r;
      size_t off = (size_t)b * CHW_ + (size_t)co * HW_ + (size_t)hc * W_ + row;
      Y[off] = Y[off] + fmaxf(acc[mt][r], 0.f);
    }
}

extern "C" void kernel_launch(void* const* d_in, const int* in_sizes, int n_in,
                              void* d_out, int out_size, void* d_ws, size_t ws_size,
                              hipStream_t stream) {
  const float* x = (const float*)d_in[0];
  const float* w_ud = (const float*)d_in[1];
  const float* w_du = (const float*)d_in[2];
  const float* w_lr = (const float*)d_in[3];
  const float* w_rl = (const float*)d_in[4];

  float* Y = (float*)d_out;  // f32 image (P1 out / P2 in); scratch later
  char* ws = (char*)d_ws;
  _Float16* Wf = (_Float16*)(ws + WS_WF_OFF);
  _Float16* carryA = (_Float16*)(ws + WS_CARRY_OFF);          // parity 0
  _Float16* carryB = carryA + CARRY_HALVES;                    // parity 1
  _Float16* YtA = (_Float16*)(ws + WS_YT_OFF);                 // 64 MB f16 image (ws)
  _Float16* F16A = (_Float16*)d_out;                           // [0, 64 MB) of d_out
  _Float16* F16B = (_Float16*)((char*)d_out + F16_IMG_BYTES);  // [64, 128 MB) of d_out

  const size_t WF_PASS = 8 * 36 * 64 * 8;

  k_wprep<<<dim3(576, 4), 256, 0, stream>>>(w_ud, w_du, w_lr, w_rl, Wf);

  if (ws_size >= WS_NEED) {
    // ---- primary: trapezoid scan; WC=8 vertical (32 strips), WC=4 horizontal (32 strips) ----
    _Float16* cb_[2] = {carryA, carryB};
    // P1: vertical fwd, x = d_in (f32, read-only), y = d_out (f32)
    k_carry0<float, float><<<dim3(16, B_), 256, 0, stream>>>(x, Y, carryA, H_, W_, 0);
    for (int n0 = 0, j = 0; n0 < H_ - 1; n0 += 8, ++j) {
      int ns = H_ - 1 - n0; if (ns > 8) ns = 8;
      k_scan3<float, float, 8, 5><<<dim3(32, B_), 512, 0, stream>>>(
          x, Y, Wf + 0 * WF_PASS, cb_[j & 1], cb_[(j + 1) & 1], H_, W_, n0, ns, +1, 0);
    }
    // P2: vertical bwd, x = d_out (f32), y = YtA (f16) [= old t1 quantization point]
    k_carry0<float, _Float16><<<dim3(16, B_), 256, 0, stream>>>(Y, YtA, carryA, H_, W_, H_ - 1);
    for (int n0 = 0, j = 0; n0 < H_ - 1; n0 += 8, ++j) {
      int ns = H_ - 1 - n0; if (ns > 8) ns = 8;
      k_scan3<float, _Float16, 8, 5><<<dim3(32, B_), 512, 0, stream>>>(
          Y, YtA, Wf + 1 * WF_PASS, cb_[j & 1], cb_[(j + 1) & 1], H_, W_, n0, ns, -1, H_ - 1);
    }
    // transpose YtA [b][c][h][w] -> F16A [b][c][w][h]
    k_t1h<<<dim3(8, 4, B_ * C_), dim3(32, 8), 0, stream>>>(YtA, F16A);
    // P3: horizontal fwd, x = F16A, y = YtA (transposed layout: S=W, L=H)
    k_carry0<_Float16, _Float16><<<dim3(8, B_), 256, 0, stream>>>(F16A, YtA, carryA, W_, H_, 0);
    for (int n0 = 0, j = 0; n0 < W_ - 1; n0 += 8, ++j) {
      int ns = W_ - 1 - n0; if (ns > 8) ns = 8;
      k_scan3<_Float16, _Float16, 4, 5><<<dim3(32, B_), 512, 0, stream>>>(
          F16A, YtA, Wf + 2 * WF_PASS, cb_[j & 1], cb_[(j + 1) & 1], W_, H_, n0, ns, +1, 0);
    }
    // P4: horizontal bwd, x = YtA, y = F16B
    k_carry0<_Float16, _Float16><<<dim3(8, B_), 256, 0, stream>>>(YtA, F16B, carryA, W_, H_, W_ - 1);
    for (int n0 = 0, j = 0; n0 < W_ - 1; n0 += 8, ++j) {
      int ns = W_ - 1 - n0; if (ns > 8) ns = 8;
      k_scan3<_Float16, _Float16, 4, 5><<<dim3(32, B_), 512, 0, stream>>>(
          YtA, F16B, Wf + 3 * WF_PASS, cb_[j & 1], cb_[(j + 1) & 1], W_, H_, n0, ns, -1, W_ - 1);
    }
    // move P4 result out of d_out (k_t2 will overwrite all of d_out), then back-transpose
    k_copy<<<2048, 256, 0, stream>>>((const float*)F16B, (float*)YtA, F16_IMG_BYTES / 16);
    k_t2<<<dim3(8, 4, B_ * C_), dim3(32, 8), 0, stream>>>(YtA, Y);
  } else {
    // ---- fallback: proven per-step path ----
    k_copy<<<2048, 256, 0, stream>>>(x, Y, B_ * C_ * H_ * W_ / 4);
    for (int i = 1; i < H_; ++i)
      k_step_v<<<dim3(W_ / 64, B_), 256, 0, stream>>>(Y, Wf + 0 * WF_PASS, i, i - 1);
    for (int i = H_ - 2; i >= 0; --i)
      k_step_v<<<dim3(W_ / 64, B_), 256, 0, stream>>>(Y, Wf + 1 * WF_PASS, i, i + 1);
    for (int i = 1; i < W_; ++i)
      k_step_h<<<dim3(H_ / 64, B_), 256, 0, stream>>>(Y, Wf + 2 * WF_PASS, i, i - 1);
    for (int i = W_ - 2; i >= 0; --i)
      k_step_h<<<dim3(H_ / 64, B_), 256, 0, stream>>>(Y, Wf + 3 * WF_PASS, i, i + 1);
  }
}

// Round 8
// 4160.899 us; speedup vs baseline: 4.0986x; 1.0131x over previous
//
#include <hip/hip_runtime.h>

#define C_ 128
#define KS_ 9
#define B_ 8
#define H_ 128
#define W_ 256
#define HW_ (H_ * W_)    // 32768
#define CHW_ (C_ * HW_)  // 4194304

typedef _Float16 half8 __attribute__((ext_vector_type(8)));
typedef float floatx4 __attribute__((ext_vector_type(4)));
typedef unsigned long long ull;

// f16 full image = 8*128*128*256*2 B
#define F16_IMG_BYTES 67108864u

// ws layout (primary path)
#define WS_WF_OFF    0u
#define WS_WF_BYTES  1179648u            // 4 passes * 294,912 B fragment weights
#define WS_CARRY_OFF 1183744u            // 2 x [b][col<=256][128ci] f16 = 2 x 524,288 B
#define CARRY_HALVES (8 * 256 * 128)     // 262,144 halves = 524,288 B per parity buffer
#define WS_YT_OFF    2232320u            // f16 image A: 64 MB
#define WS_NEED      (WS_YT_OFF + F16_IMG_BYTES)  // 69,341,184

__device__ __forceinline__ int imin(int a, int b) { return a < b ? a : b; }
__device__ __forceinline__ int imax(int a, int b) { return a > b ? a : b; }

// ---------------- utility kernels ----------------
__global__ void k_copy(const float* __restrict__ in, float* __restrict__ out, int n4) {
  int i = blockIdx.x * blockDim.x + threadIdx.x;
  int stride = gridDim.x * blockDim.x;
  const floatx4* ip = (const floatx4*)in;
  floatx4* op = (floatx4*)out;
  for (; i < n4; i += stride) op[i] = ip[i];
}

// weight prep: fp32 [co][ci][kk] -> f16 A-fragment order
// idx = (((mt8)*36 + ks)*64 + lane)*8 + j ; co = mt8*16 + (lane&15); k = ks*32 + q*8 + j
__global__ void k_wprep(const float* w0, const float* w1, const float* w2, const float* w3,
                        _Float16* __restrict__ wf) {
  const float* Wp[4] = {w0, w1, w2, w3};
  const float* W = Wp[blockIdx.y];
  _Float16* out = wf + (size_t)blockIdx.y * (8 * 36 * 64 * 8);
  int idx = blockIdx.x * 256 + threadIdx.x;
  if (idx >= 8 * 36 * 64 * 8) return;
  int j = idx & 7;
  int lane = (idx >> 3) & 63;
  int ks = (idx >> 9) % 36;
  int mt = (idx >> 9) / 36;
  int co = mt * 16 + (lane & 15);
  int k = ks * 32 + ((lane >> 4) & 3) * 8 + j;
  int kk = k >> 7, ci = k & 127;
  out[idx] = (_Float16)W[((size_t)co * C_ + ci) * KS_ + kk];
}

// initial carry row for a pass: cout[b][col][ci] = (f16) imgX[b][ci][istart][col]
// also writes imgY row istart (y[0] = x[0]).
template <typename XT, typename YT>
__global__ void k_carry0(const XT* __restrict__ imgX, YT* __restrict__ imgY,
                         _Float16* __restrict__ cout_, int S, int L, int istart) {
  int b = blockIdx.y;
  int e = blockIdx.x * 256 + threadIdx.x;  // (col, ci-group-of-8)
  if (e >= L * 16) return;
  int col = e >> 4, ci0 = (e & 15) * 8;
  union { ull u[2]; _Float16 h[8]; } pk;
#pragma unroll
  for (int u2 = 0; u2 < 8; ++u2) {
    size_t off = ((size_t)(b * C_ + ci0 + u2) * S + istart) * L + col;
    float v = (float)imgX[off];
    pk.h[u2] = (_Float16)v;
    imgY[off] = (YT)v;
  }
  ull* dst = (ull*)(cout_ + ((size_t)b * L + col) * 128 + ci0);
  dst[0] = pk.u[0];
  dst[1] = pk.u[1];
}

// transpose f16 [b][c][h][w] -> f16 [b][c][w][h]
__global__ void k_t1h(const _Float16* __restrict__ in, _Float16* __restrict__ out) {
  __shared__ _Float16 tile[32][33];
  size_t pbase = (size_t)blockIdx.z * HW_;
  int h0 = blockIdx.y * 32, w0 = blockIdx.x * 32;
  int tx = threadIdx.x, ty = threadIdx.y;
  for (int i = 0; i < 32; i += 8)
    tile[ty + i][tx] = in[pbase + (size_t)(h0 + ty + i) * W_ + (w0 + tx)];
  __syncthreads();
  for (int i = 0; i < 32; i += 8)
    out[pbase + (size_t)(w0 + ty + i) * H_ + (h0 + tx)] = tile[tx][ty + i];
}

// transpose f16 [b][c][w][h] -> fp32 NCHW
__global__ void k_t2(const _Float16* __restrict__ in, float* __restrict__ out) {
  __shared__ float tile[32][33];
  size_t pbase = (size_t)blockIdx.z * HW_;
  int h0 = blockIdx.y * 32, w0 = blockIdx.x * 32;
  int tx = threadIdx.x, ty = threadIdx.y;
  for (int i = 0; i < 32; i += 8)
    tile[ty + i][tx] = (float)in[pbase + (size_t)(w0 + ty + i) * H_ + (h0 + tx)];
  __syncthreads();
  for (int i = 0; i < 32; i += 8)
    out[pbase + (size_t)(h0 + ty + i) * W_ + (w0 + tx)] = tile[tx][ty + i];
}

// ---------------- trapezoid scan kernel: P=8 steps per launch, no cross-WG sync --------------
// 8 waves (512 thr). Wave-pair K-split: pair g = wave>>1 owns m-tiles {2g,2g+1}; wave h =
// wave&1 computes K-half h. Carry lives in a SINGLE LDS buffer updated in place: step p+1
// reads exactly [lo(p+1)-4, hi(p+1)+4) subset of [lo(p), hi(p)) + zero guards, and the
// mid-step barrier separates all reads of the old carry from the in-place overwrite.
// Batched exchange: all tiles' partner-half partials go to Sc[], ONE barrier, then all
// epilogues (own half kept in regs). Next step's x (pass-constant imgX) prefetched before
// the end barrier. LDS rows stride 136 halves (16B-aligned -> single ds_read_b128,
// bank-audit: 8 accesses/bank uniform, conflict-free).
template <typename XT, typename YT, int WC, int MAXT>
__global__ __launch_bounds__(512, 2) void k_scan3(
    const XT* __restrict__ imgX, YT* __restrict__ imgY,
    const _Float16* __restrict__ Wf, const _Float16* __restrict__ cin,
    _Float16* __restrict__ cout_,
    int S, int L, int n0, int nsteps, int dir, int istart) {
  constexpr int MAXW = WC + 72;        // cols [c0-36, c0+WC+36); 4-col zero guards each side
  constexpr int BSZ = MAXW * 136;      // 136-half row stride: 272 B, 16B-aligned
  __shared__ _Float16 Bl[BSZ];         // single carry buffer (in-place update)
  __shared__ floatx4 Sc[MAXT][8][64];  // partner-half partials for all tiles of a step
  const int c0 = blockIdx.x * WC;
  const int b = blockIdx.y;
  const int t = threadIdx.x;
  const int lane = t & 63, wave = t >> 6;
  const int q = lane >> 4, m = lane & 15;
  const int h = wave & 1;              // K-half
  const int g = wave >> 1;             // co-pair group (m-tiles 2g, 2g+1)

  // A-fragments: m-tiles {2g, 2g+1}, K-half h (ks = h*18 + i): 36 half8 = 144 VGPRs
  half8 A0[18], A1[18];
  {
    const half8* wp2 = (const half8*)Wf;
#pragma unroll
    for (int i = 0; i < 18; ++i) {
      A0[i] = wp2[((g * 2 + 0) * 36 + h * 18 + i) * 64 + lane];
      A1[i] = wp2[((g * 2 + 1) * 36 + h * 18 + i) * 64 + lane];
    }
  }

  // zero Bl (conv zero-padding guards); slots of 8 halves = 2 ull stores
  for (int i = t * 8; i < BSZ; i += 4096) {
    ull* z = (ull*)(&Bl[i]);
    z[0] = 0ull;
    z[1] = 0ull;
  }
  __syncthreads();

  // load carry row n0: cols [c0-32, c0+WC+32) ∩ [0,L) into Bl
  {
    const int NCH = (WC + 64) * 16;
    for (int e = t; e < NCH; e += 512) {
      const int lcol = e >> 4;
      const int col = c0 - 32 + lcol;
      if (col >= 0 && col < L) {
        const int ci0 = (e & 15) * 8;
        const ull* src = (const ull*)(cin + ((size_t)b * L + col) * 128 + ci0);
        ull* dst = (ull*)(&Bl[(lcol + 4) * 136 + ci0]);
        dst[0] = src[0];
        dst[1] = src[1];
      }
    }
  }

  // bounds + x prefetch for step 1 (imgX is pass-constant: no carry dependency)
  int row, lo, hi, tt0, ntile;
  size_t rbase;
  float xv[MAXT][4];
  {
    row = istart + dir * (n0 + 1);
    const int ext = 32 - 4;
    lo = imax(c0 - ext, 0);
    hi = imin(c0 + WC + ext, L);
    tt0 = -((c0 - lo + 15) >> 4);
    ntile = ((hi - c0 + 15) >> 4) - tt0;
    rbase = ((size_t)(b * C_ + wave * 16) * S + row) * L;
#pragma unroll
    for (int u = 0; u < MAXT; ++u) {
      if (u >= ntile) break;
      const int col = c0 + (tt0 + u) * 16 + m;
      const bool ld2 = (col >= lo) && (col < hi);
#pragma unroll
      for (int r = 0; r < 4; ++r)
        xv[u][r] = ld2 ? (float)imgX[rbase + (size_t)(q * 4 + r) * (S * L) + col] : 0.f;
    }
  }
  __syncthreads();  // carry ready in Bl

  for (int p = 1; p <= nsteps; ++p) {
    // ---- GEMM phase: all tiles; own half -> xa regs, partner half -> Sc ----
    floatx4 xa[MAXT];
#pragma unroll
    for (int u = 0; u < MAXT; ++u) {
      if (u >= ntile) break;
      const int ti = tt0 + u;
      floatx4 aA = {0.f, 0.f, 0.f, 0.f}, aB = {0.f, 0.f, 0.f, 0.f};
      const int lbase = ti * 16 + m + 32;  // lcol for kk=0 tap (col + kk - 4 -> +36-4)
#pragma unroll
      for (int i = 0; i < 18; ++i) {
        const int ks = h * 18 + i;
        const int kk = ks >> 2;
        const int ci0 = (ks & 3) * 32 + q * 8;
        const half8 bf = *(const half8*)(Bl + (lbase + kk) * 136 + ci0);  // ds_read_b128
        aA = __builtin_amdgcn_mfma_f32_16x16x32_f16(A0[i], bf, aA, 0, 0, 0);
        aB = __builtin_amdgcn_mfma_f32_16x16x32_f16(A1[i], bf, aB, 0, 0, 0);
      }
      Sc[u][wave][lane] = h ? aA : aB;  // partner's m-tile half
      xa[u] = h ? aB : aA;              // own m-tile (2g+h = wave) half
    }
    __syncthreads();  // Sc ready AND all Bl reads done -> in-place overwrite safe

    // ---- epilogue phase: combine halves, store imgY, write new carry into Bl ----
#pragma unroll
    for (int u = 0; u < MAXT; ++u) {
      if (u >= ntile) break;
      const int ti = tt0 + u;
      const floatx4 ac = xa[u] + Sc[u][wave ^ 1][lane];
      const int col = c0 + ti * 16 + m;
      const bool instrip = (col >= c0) && (col < c0 + WC);
      const bool inlds = (col >= lo) && (col < hi);
      union { ull uu; _Float16 h4[4]; } pk;
#pragma unroll
      for (int r = 0; r < 4; ++r) {
        const float y = xv[u][r] + fmaxf(ac[r], 0.f);
        pk.h4[r] = (_Float16)y;
        if (instrip)
          imgY[rbase + (size_t)(q * 4 + r) * (S * L) + col] = (YT)y;
      }
      if (inlds)
        *(ull*)(Bl + (col - c0 + 36) * 136 + wave * 16 + q * 4) = pk.uu;
    }

    // ---- prefetch next step's bounds + x before the end barrier ----
    if (p < nsteps) {
      row = istart + dir * (n0 + p + 1);
      const int ext = 32 - 4 * (p + 1);
      lo = imax(c0 - ext, 0);
      hi = imin(c0 + WC + ext, L);
      tt0 = -((c0 - lo + 15) >> 4);
      ntile = ((hi - c0 + 15) >> 4) - tt0;
      rbase = ((size_t)(b * C_ + wave * 16) * S + row) * L;
#pragma unroll
      for (int u = 0; u < MAXT; ++u) {
        if (u >= ntile) break;
        const int col = c0 + (tt0 + u) * 16 + m;
        const bool ld2 = (col >= lo) && (col < hi);
#pragma unroll
        for (int r = 0; r < 4; ++r)
          xv[u][r] = ld2 ? (float)imgX[rbase + (size_t)(q * 4 + r) * (S * L) + col] : 0.f;
      }
    }
    __syncthreads();  // new carry complete; Sc consumable by next GEMM phase
  }

  // publish own strip's carry (row n0+nsteps); each (lc, ci-group) = 8 halves = 2 ull
  {
    for (int e = t; e < WC * 16; e += 512) {
      const int lc = e >> 4, ci0 = (e & 15) * 8;
      ull* dst = (ull*)(cout_ + ((size_t)b * L + (c0 + lc)) * 128 + ci0);
      const ull* src = (const ull*)(Bl + (lc + 36) * 136 + ci0);
      dst[0] = src[0];
      dst[1] = src[1];
    }
  }
}

// ---------------- fallback path (round-2, proven): per-step kernels ----------------
__device__ __forceinline__ void gemm_acc_fb(const _Float16* Bl, const _Float16* __restrict__ Wfrag,
                                            int wrow_base, int lane, floatx4* acc) {
  const int q = lane >> 4;
  const half8* wfp = (const half8*)Wfrag + lane;
  for (int ks = 0; ks < 36; ++ks) {
    int k0 = ks * 32 + q * 8;
    int kk = k0 >> 7;
    int ci0 = k0 & 127;
    half8 bf = *(const half8*)&Bl[(size_t)(wrow_base + kk) * C_ + ci0];
    const half8* wp = wfp + ks * 64;
#pragma unroll
    for (int mt = 0; mt < 8; ++mt)
      acc[mt] = __builtin_amdgcn_mfma_f32_16x16x32_f16(wp[mt * 36 * 64], bf, acc[mt], 0, 0, 0);
  }
}

__global__ __launch_bounds__(256) void k_step_v(float* __restrict__ Y,
                                                const _Float16* __restrict__ Wfrag,
                                                int row, int prev) {
  __shared__ _Float16 Bl[80 * 128];
  const int b = blockIdx.y, w0 = blockIdx.x * 64, t = threadIdx.x;
  {
    const float* base = Y + (size_t)b * CHW_ + (size_t)prev * W_;
#pragma unroll
    for (int it = 0; it < 10; ++it) {
      int c = it * 256 + t;
      int ci = c / 20, c4 = c % 20;
      int wst = w0 - 8 + c4 * 4;
      const float* p = base + (size_t)ci * HW_ + wst;
      float v[4];
      if (wst >= 0 && wst + 4 <= W_) {
        floatx4 u = *(const floatx4*)p;
        v[0] = u[0]; v[1] = u[1]; v[2] = u[2]; v[3] = u[3];
      } else {
#pragma unroll
        for (int j = 0; j < 4; ++j) { int w = wst + j; v[j] = (w >= 0 && w < W_) ? p[j] : 0.f; }
      }
      int wl = c4 * 4;
#pragma unroll
      for (int j = 0; j < 4; ++j) Bl[(wl + j) * C_ + ci] = (_Float16)v[j];
    }
  }
  __syncthreads();
  const int lane = t & 63, wave = t >> 6, q = lane >> 4, l15 = lane & 15;
  floatx4 acc[8];
#pragma unroll
  for (int mt = 0; mt < 8; ++mt) acc[mt] = (floatx4){0.f, 0.f, 0.f, 0.f};
  gemm_acc_fb(Bl, Wfrag, wave * 16 + l15 + 4, lane, acc);
  const int wcol = w0 + wave * 16 + l15;
#pragma unroll
  for (int mt = 0; mt < 8; ++mt)
#pragma unroll
    for (int r = 0; r < 4; ++r) {
      int co = mt * 16 + q * 4 + r;
      size_t off = (size_t)b * CHW_ + (size_t)co * HW_ + (size_t)row * W_ + wcol;
      Y[off] = Y[off] + fmaxf(acc[mt][r], 0.f);
    }
}

__global__ __launch_bounds__(256) void k_step_h(float* __restrict__ Y,
                                                const _Float16* __restrict__ Wfrag,
                                                int row, int prev) {
  __shared__ _Float16 Bl[80 * 128];
  const int b = blockIdx.y, h0 = blockIdx.x * 64, t = threadIdx.x;
  {
    const float* base = Y + (size_t)b * CHW_ + prev;
    for (int e = t; e < 80 * 128; e += 256) {
      int hl = e >> 7, ci = e & 127, h = h0 - 8 + hl;
      float v = 0.f;
      if (h >= 0 && h < H_) v = base[(size_t)ci * HW_ + (size_t)h * W_];
      Bl[hl * C_ + ci] = (_Float16)v;
    }
  }
  __syncthreads();
  const int lane = t & 63, wave = t >> 6, q = lane >> 4, l15 = lane & 15;
  floatx4 acc[8];
#pragma unroll
  for (int mt = 0; mt < 8; ++mt) acc[mt] = (floatx4){0.f, 0.f, 0.f, 0.f};
  gemm_acc_fb(Bl, Wfrag, wave * 16 + l15 + 4, lane, acc);
  const int hc = h0 + wave * 16 + l15;
#pragma unroll
  for (int mt = 0; mt < 8; ++mt)
#pragma unroll
    for (int r = 0; r < 4; ++r) {
      int co = mt * 16 + q * 4 + r;
      size_t off = (size_t)b * CHW_ + (size_t)co * HW_ + (size_t)hc * W_ + row;
      Y[off] = Y[off] + fmaxf(acc[mt][r], 0.f);
    }
}

extern "C" void kernel_launch(void* const* d_in, const int* in_sizes, int n_in,
                              void* d_out, int out_size, void* d_ws, size_t ws_size,
                              hipStream_t stream) {
  const float* x = (const float*)d_in[0];
  const float* w_ud = (const float*)d_in[1];
  const float* w_du = (const float*)d_in[2];
  const float* w_lr = (const float*)d_in[3];
  const float* w_rl = (const float*)d_in[4];

  float* Y = (float*)d_out;  // f32 image (P1 out / P2 in); scratch later
  char* ws = (char*)d_ws;
  _Float16* Wf = (_Float16*)(ws + WS_WF_OFF);
  _Float16* carryA = (_Float16*)(ws + WS_CARRY_OFF);          // parity 0
  _Float16* carryB = carryA + CARRY_HALVES;                    // parity 1
  _Float16* YtA = (_Float16*)(ws + WS_YT_OFF);                 // 64 MB f16 image (ws)
  _Float16* F16A = (_Float16*)d_out;                           // [0, 64 MB) of d_out
  _Float16* F16B = (_Float16*)((char*)d_out + F16_IMG_BYTES);  // [64, 128 MB) of d_out

  const size_t WF_PASS = 8 * 36 * 64 * 8;

  k_wprep<<<dim3(576, 4), 256, 0, stream>>>(w_ud, w_du, w_lr, w_rl, Wf);

  if (ws_size >= WS_NEED) {
    // ---- primary: trapezoid scan; WC=8 vertical (32 strips), WC=4 horizontal (32 strips) ----
    _Float16* cb_[2] = {carryA, carryB};
    // P1: vertical fwd, x = d_in (f32, read-only), y = d_out (f32)
    k_carry0<float, float><<<dim3(16, B_), 256, 0, stream>>>(x, Y, carryA, H_, W_, 0);
    for (int n0 = 0, j = 0; n0 < H_ - 1; n0 += 8, ++j) {
      int ns = H_ - 1 - n0; if (ns > 8) ns = 8;
      k_scan3<float, float, 8, 5><<<dim3(32, B_), 512, 0, stream>>>(
          x, Y, Wf + 0 * WF_PASS, cb_[j & 1], cb_[(j + 1) & 1], H_, W_, n0, ns, +1, 0);
    }
    // P2: vertical bwd, x = d_out (f32), y = YtA (f16) [= old t1 quantization point]
    k_carry0<float, _Float16><<<dim3(16, B_), 256, 0, stream>>>(Y, YtA, carryA, H_, W_, H_ - 1);
    for (int n0 = 0, j = 0; n0 < H_ - 1; n0 += 8, ++j) {
      int ns = H_ - 1 - n0; if (ns > 8) ns = 8;
      k_scan3<float, _Float16, 8, 5><<<dim3(32, B_), 512, 0, stream>>>(
          Y, YtA, Wf + 1 * WF_PASS, cb_[j & 1], cb_[(j + 1) & 1], H_, W_, n0, ns, -1, H_ - 1);
    }
    // transpose YtA [b][c][h][w] -> F16A [b][c][w][h]
    k_t1h<<<dim3(8, 4, B_ * C_), dim3(32, 8), 0, stream>>>(YtA, F16A);
    // P3: horizontal fwd, x = F16A, y = YtA (transposed layout: S=W, L=H)
    k_carry0<_Float16, _Float16><<<dim3(8, B_), 256, 0, stream>>>(F16A, YtA, carryA, W_, H_, 0);
    for (int n0 = 0, j = 0; n0 < W_ - 1; n0 += 8, ++j) {
      int ns = W_ - 1 - n0; if (ns > 8) ns = 8;
      k_scan3<_Float16, _Float16, 4, 4><<<dim3(32, B_), 512, 0, stream>>>(
          F16A, YtA, Wf + 2 * WF_PASS, cb_[j & 1], cb_[(j + 1) & 1], W_, H_, n0, ns, +1, 0);
    }
    // P4: horizontal bwd, x = YtA, y = F16B
    k_carry0<_Float16, _Float16><<<dim3(8, B_), 256, 0, stream>>>(YtA, F16B, carryA, W_, H_, W_ - 1);
    for (int n0 = 0, j = 0; n0 < W_ - 1; n0 += 8, ++j) {
      int ns = W_ - 1 - n0; if (ns > 8) ns = 8;
      k_scan3<_Float16, _Float16, 4, 4><<<dim3(32, B_), 512, 0, stream>>>(
          YtA, F16B, Wf + 3 * WF_PASS, cb_[j & 1], cb_[(j + 1) & 1], W_, H_, n0, ns, -1, W_ - 1);
    }
    // move P4 result out of d_out (k_t2 will overwrite all of d_out), then back-transpose
    k_copy<<<2048, 256, 0, stream>>>((const float*)F16B, (float*)YtA, F16_IMG_BYTES / 16);
    k_t2<<<dim3(8, 4, B_ * C_), dim3(32, 8), 0, stream>>>(YtA, Y);
  } else {
    // ---- fallback: proven per-step path ----
    k_copy<<<2048, 256, 0, stream>>>(x, Y, B_ * C_ * H_ * W_ / 4);
    for (int i = 1; i < H_; ++i)
      k_step_v<<<dim3(W_ / 64, B_), 256, 0, stream>>>(Y, Wf + 0 * WF_PASS, i, i - 1);
    for (int i = H_ - 2; i >= 0; --i)
      k_step_v<<<dim3(W_ / 64, B_), 256, 0, stream>>>(Y, Wf + 1 * WF_PASS, i, i + 1);
    for (int i = 1; i < W_; ++i)
      k_step_h<<<dim3(H_ / 64, B_), 256, 0, stream>>>(Y, Wf + 2 * WF_PASS, i, i - 1);
    for (int i = W_ - 2; i >= 0; --i)
      k_step_h<<<dim3(H_ / 64, B_), 256, 0, stream>>>(Y, Wf + 3 * WF_PASS, i, i + 1);
  }
}